// Round 7
// baseline (589.134 us; speedup 1.0000x reference)
//
#include <hip/hip_runtime.h>
#include <hip/hip_bf16.h>

// ---------------- problem constants (static pyramid) ----------------
#define NB 4
#define LQ 5440
#define DM 256
#define NH 8
#define NL 4
#define NP 4
#define OFFD 32
#define DH 32
#define MTOT (NB * LQ)             // 21760
#define OEN (NH * NL * NP * OFFD)  // 4096
#define NGRP (NH * NL * NP)        // 128

typedef __attribute__((ext_vector_type(8))) short bf16x8;
typedef __attribute__((ext_vector_type(4))) float f32x4;
typedef unsigned int u32;

__device__ __forceinline__ float bf2f(unsigned short u) {
    union { unsigned int i; float f; } v; v.i = ((unsigned int)u) << 16; return v.f;
}
// cheap RNE f32->bf16 (no NaN path; all values finite here)
__device__ __forceinline__ unsigned short f2bf(float x) {
    u32 u = __float_as_uint(x);
    u = u + 0x7fffu + ((u >> 16) & 1u);
    return (unsigned short)(u >> 16);
}
__device__ __forceinline__ u32 pk2(float a, float b) {
    u32 ua = __float_as_uint(a), ub = __float_as_uint(b);
    ua = ua + 0x7fffu + ((ua >> 16) & 1u);
    ub = ub + 0x7fffu + ((ub >> 16) & 1u);
    return (ua >> 16) | (ub & 0xffff0000u);
}
__device__ __forceinline__ float silu(float x) {
    float e = __expf(-x);
    return x * __builtin_amdgcn_rcpf(1.0f + e);   // v_rcp_f32, ~1 ulp
}

// ---------------- fp32 -> bf16 conversions ----------------
__global__ __launch_bounds__(256) void k_cvt2(
    const float* __restrict__ A, unsigned short* __restrict__ Ao,
    const float* __restrict__ B, unsigned short* __restrict__ Bo, int n4)
{
    int i = blockIdx.x * 256 + threadIdx.x;
    if (i >= n4) return;
    const float* src = blockIdx.y ? B : A;
    unsigned short* dst = blockIdx.y ? Bo : Ao;
    float4 v = *(const float4*)(src + (size_t)i * 4);
    ushort4 o;
    o.x = f2bf(v.x); o.y = f2bf(v.y); o.z = f2bf(v.z); o.w = f2bf(v.w);
    *(ushort4*)(dst + (size_t)i * 4) = o;
}
// weight tensors + Rb prepack (y==3)
__global__ __launch_bounds__(256) void k_cvt3(
    const float* __restrict__ A, unsigned short* __restrict__ Ao, int nA4,
    const float* __restrict__ B, unsigned short* __restrict__ Bo, int nB4,
    const float* __restrict__ C, unsigned short* __restrict__ Co, int nC4,
    const float* __restrict__ SW, const float* __restrict__ AW,
    unsigned short* __restrict__ Rb)
{
    int i = blockIdx.x * 256 + threadIdx.x;
    if (blockIdx.y == 3) {
        if (i < 65536) {
            int gg = i >> 9, jo = (i >> 5) & 15, d = i & 31;
            float v = 0.f;
            if (jo == 0)      v = SW[(gg * 32 + d) * 2 + 0];
            else if (jo == 1) v = SW[(gg * 32 + d) * 2 + 1];
            else if (jo == 2) v = AW[gg * 32 + d];
            Rb[i] = f2bf(v);
        }
        return;
    }
    const float* src; unsigned short* dst; int n4;
    if (blockIdx.y == 0)      { src = A; dst = Ao; n4 = nA4; }
    else if (blockIdx.y == 1) { src = B; dst = Bo; n4 = nB4; }
    else                      { src = C; dst = Co; n4 = nC4; }
    if (i >= n4) return;
    float4 v = *(const float4*)(src + (size_t)i * 4);
    ushort4 o;
    o.x = f2bf(v.x); o.y = f2bf(v.y); o.z = f2bf(v.z); o.w = f2bf(v.w);
    *(ushort4*)(dst + (size_t)i * 4) = o;
}

// ============================================================================
// Pipelined MFMA GEMM skeleton: 128x128 tile, BK=64, XOR-swizzled LDS,
// REGISTER prefetch of iter i+1 issued before MFMA of iter i -> the vmcnt
// wait at ds_write time covers long-completed loads (no barrier drain).
// LDS slot (row=c>>3, q=c&7) holds GLOBAL chunk (row, q ^ (row&7)).
// C/D layout (verified): col = lane&15, row = (lane>>4)*4 + reg.
// ============================================================================

// ---------------- stage B: oe GEMM (A=We, B=Q) + silu + MFMA reduction ------
__global__ __launch_bounds__(256) void k_oe_mfma(
    const unsigned short* __restrict__ Qb,   // (21760,256) bf16
    const unsigned short* __restrict__ Wb,   // (4096,256) bf16
    const unsigned short* __restrict__ Rb,   // (128,16,32) bf16 reduction frags
    const float* __restrict__ SB,    // (128,2)
    const float* __restrict__ AB,    // (128)
    float* __restrict__ offs_out,    // (M,128,2)
    float* __restrict__ aw_out)      // (M,128)
{
    __shared__ short sA[128 * 64];   // Q rows
    __shared__ short sB[128 * 64];   // We rows
    int tid = threadIdx.x;
    int n0 = blockIdx.x * 128;   // We/n fastest-varying -> blocks share Q via L2
    int m0 = blockIdx.y * 128;

    int lane = tid & 63;
    int w = tid >> 6;
    int wA = w >> 1;            // We half (mfma-m)
    int wB = w & 1;             // Q half (mfma-n)
    int lcol = lane & 15, quad = lane >> 4;

    int srow = tid >> 3;
    int sq = (tid & 7) ^ (srow & 7);
    const short* gA = (const short*)Qb + (size_t)(m0 + srow) * 256 + sq * 8;
    const short* gB = (const short*)Wb + (size_t)(n0 + srow) * 256 + sq * 8;

    f32x4 acc[4][4] = {};   // [We-tile i][Q-tile j]

    const short* pq = sA + (wB * 64 + lcol) * 64;   // Q fragments (B operand)
    const short* pw = sB + (wA * 64 + lcol) * 64;   // We fragments (A operand)
    int rx7 = lcol & 7;
    int qa0 = (quad ^ rx7) * 8;
    int qa1 = ((4 + quad) ^ rx7) * 8;

    uint4 ra[4], rb2[4];
#pragma unroll
    for (int j = 0; j < 4; j++) {
        ra[j]  = *(const uint4*)(gA + j * 32 * 256);
        rb2[j] = *(const uint4*)(gB + j * 32 * 256);
    }
#pragma unroll
    for (int it = 0; it < 4; it++) {
        uint4 na[4], nb[4];
        if (it < 3) {
            const short* qA = gA + (it + 1) * 64;
            const short* qB = gB + (it + 1) * 64;
#pragma unroll
            for (int j = 0; j < 4; j++) {
                na[j] = *(const uint4*)(qA + j * 32 * 256);
                nb[j] = *(const uint4*)(qB + j * 32 * 256);
            }
        }
        __syncthreads();   // prior iter's ds_reads complete before overwrite
#pragma unroll
        for (int j = 0; j < 4; j++) {
            *(uint4*)((char*)sA + j * 4096 + tid * 16) = ra[j];
            *(uint4*)((char*)sB + j * 4096 + tid * 16) = rb2[j];
        }
        __syncthreads();
        bf16x8 a[4][2], b[4][2];
#pragma unroll
        for (int i = 0; i < 4; i++) {
            a[i][0] = *(const bf16x8*)(pw + i * 16 * 64 + qa0);  // We
            a[i][1] = *(const bf16x8*)(pw + i * 16 * 64 + qa1);
            b[i][0] = *(const bf16x8*)(pq + i * 16 * 64 + qa0);  // Q
            b[i][1] = *(const bf16x8*)(pq + i * 16 * 64 + qa1);
        }
#pragma unroll
        for (int kh = 0; kh < 2; kh++)
#pragma unroll
            for (int i = 0; i < 4; i++)
#pragma unroll
                for (int j = 0; j < 4; j++)
                    acc[i][j] = __builtin_amdgcn_mfma_f32_16x16x32_bf16(
                        a[i][kh], b[j][kh], acc[i][j], 0, 0, 0);
        if (it < 3) {
#pragma unroll
            for (int j = 0; j < 4; j++) { ra[j] = na[j]; rb2[j] = nb[j]; }
        }
    }

    // ---- epilogue: silu -> bf16 pack (registers) -> MFMA reduction ----
    u32 ps[4][4][2];
#pragma unroll
    for (int i = 0; i < 4; i++)
#pragma unroll
        for (int j = 0; j < 4; j++) {
            ps[i][j][0] = pk2(silu(acc[i][j][0]), silu(acc[i][j][1]));
            ps[i][j][1] = pk2(silu(acc[i][j][2]), silu(acc[i][j][3]));
        }

    int srcbase = (quad & 1) * 32 + lcol;
    bool hi = quad >= 2;
    f32x4 zero = {};
#pragma unroll
    for (int g = 0; g < 2; g++) {
        int gg = (n0 + wA * 64 + g * 32) >> 5;
        bf16x8 afrag = *(const bf16x8*)(Rb + ((size_t)(gg * 16 + lcol) * 32 + quad * 8));
        float sb0 = SB[gg * 2 + 0], sb1 = SB[gg * 2 + 1], ab = AB[gg];
#pragma unroll
        for (int j = 0; j < 4; j++) {
            union { u32 u[4]; bf16x8 v; } bf;
#pragma unroll
            for (int b = 0; b < 2; b++) {
                int s = srcbase + b * 16;
#pragma unroll
                for (int c = 0; c < 2; c++) {
                    u32 x0 = (u32)__shfl((int)ps[2 * g + 0][j][c], s);
                    u32 x1 = (u32)__shfl((int)ps[2 * g + 1][j][c], s);
                    bf.u[b * 2 + c] = hi ? x1 : x0;
                }
            }
            f32x4 d2 = __builtin_amdgcn_mfma_f32_16x16x32_bf16(afrag, bf.v, zero, 0, 0, 0);
            if (quad == 0) {
                int m = m0 + wB * 64 + j * 16 + lcol;
                size_t oi = ((size_t)m * NGRP + gg) * 2;
                offs_out[oi + 0] = d2[0] + sb0;
                offs_out[oi + 1] = d2[1] + sb1;
                aw_out[(size_t)m * NGRP + gg] = d2[2] + ab;
            }
        }
    }
}

// ---------------- stage A: value projection (pipelined, swapped operands) ----
__global__ __launch_bounds__(256) void k_value_mfma(
    const unsigned short* __restrict__ Xb,   // (21760,256) bf16
    const unsigned short* __restrict__ Wvb,  // (256,256) bf16 (n,k)
    const float* __restrict__ bias,          // (256)
    unsigned short* __restrict__ Vtb)        // (4,8,5440,32) bf16
{
    __shared__ short sA[128 * 64];   // X rows
    __shared__ short sB[128 * 64];   // Wv rows
    int tid = threadIdx.x;
    int n0 = blockIdx.x * 128;
    int m0 = blockIdx.y * 128;
    int lane = tid & 63;
    int w = tid >> 6;
    int wA = w >> 1;            // Wv half (mfma-m)
    int wB = w & 1;             // X half (mfma-n)
    int lcol = lane & 15, quad = lane >> 4;

    int srow = tid >> 3;
    int sq = (tid & 7) ^ (srow & 7);
    const short* gA = (const short*)Xb + (size_t)(m0 + srow) * 256 + sq * 8;
    const short* gB = (const short*)Wvb + (size_t)(n0 + srow) * 256 + sq * 8;

    f32x4 acc[4][4] = {};   // [Wv-tile i][X-tile j]
    const short* px = sA + (wB * 64 + lcol) * 64;
    const short* pw = sB + (wA * 64 + lcol) * 64;
    int rx7 = lcol & 7;
    int qa0 = (quad ^ rx7) * 8;
    int qa1 = ((4 + quad) ^ rx7) * 8;

    uint4 ra[4], rb2[4];
#pragma unroll
    for (int j = 0; j < 4; j++) {
        ra[j]  = *(const uint4*)(gA + j * 32 * 256);
        rb2[j] = *(const uint4*)(gB + j * 32 * 256);
    }
#pragma unroll
    for (int it = 0; it < 4; it++) {
        uint4 na[4], nb[4];
        if (it < 3) {
            const short* qA = gA + (it + 1) * 64;
            const short* qB = gB + (it + 1) * 64;
#pragma unroll
            for (int j = 0; j < 4; j++) {
                na[j] = *(const uint4*)(qA + j * 32 * 256);
                nb[j] = *(const uint4*)(qB + j * 32 * 256);
            }
        }
        __syncthreads();
#pragma unroll
        for (int j = 0; j < 4; j++) {
            *(uint4*)((char*)sA + j * 4096 + tid * 16) = ra[j];
            *(uint4*)((char*)sB + j * 4096 + tid * 16) = rb2[j];
        }
        __syncthreads();
        bf16x8 a[4][2], b[4][2];
#pragma unroll
        for (int i = 0; i < 4; i++) {
            a[i][0] = *(const bf16x8*)(pw + i * 16 * 64 + qa0);  // Wv
            a[i][1] = *(const bf16x8*)(pw + i * 16 * 64 + qa1);
            b[i][0] = *(const bf16x8*)(px + i * 16 * 64 + qa0);  // X
            b[i][1] = *(const bf16x8*)(px + i * 16 * 64 + qa1);
        }
#pragma unroll
        for (int kh = 0; kh < 2; kh++)
#pragma unroll
            for (int i = 0; i < 4; i++)
#pragma unroll
                for (int j = 0; j < 4; j++)
                    acc[i][j] = __builtin_amdgcn_mfma_f32_16x16x32_bf16(
                        a[i][kh], b[j][kh], acc[i][j], 0, 0, 0);
        if (it < 3) {
#pragma unroll
            for (int j = 0; j < 4; j++) { ra[j] = na[j]; rb2[j] = nb[j]; }
        }
    }

#pragma unroll
    for (int i = 0; i < 4; i++) {
        int nb4 = n0 + wA * 64 + i * 16 + quad * 4;   // 4 consecutive n
        int h = nb4 >> 5, db = nb4 & 31;
        float4 b4 = *(const float4*)&bias[nb4];
#pragma unroll
        for (int j = 0; j < 4; j++) {
            int m = m0 + wB * 64 + j * 16 + lcol;
            int b = m / LQ, q = m - b * LQ;
            u32 lo = pk2(acc[i][j][0] + b4.x, acc[i][j][1] + b4.y);
            u32 hi2 = pk2(acc[i][j][2] + b4.z, acc[i][j][3] + b4.w);
            char* dst = (char*)Vtb + ((((size_t)b * NH + h) * LQ + q) * DH + db) * 2;
            *(uint2*)dst = make_uint2(lo, hi2);
        }
    }
}

// ---------------- stage D: output projection (pipelined) ----------------
__global__ __launch_bounds__(256) void k_out_mfma(
    const unsigned short* __restrict__ Xb,   // (21760,256) bf16 attn
    const unsigned short* __restrict__ Wob,  // (256,256) bf16 (n,k)
    const float* __restrict__ bias,          // (256)
    float* __restrict__ Out)                 // (21760,256) fp32
{
    __shared__ short sA[128 * 64];
    __shared__ short sB[128 * 64];
    int tid = threadIdx.x;
    int n0 = blockIdx.x * 128;
    int m0 = blockIdx.y * 128;
    int lane = tid & 63;
    int w = tid >> 6;
    int wm = w >> 1, wn = w & 1;
    int lcol = lane & 15, lrow = lane >> 4;

    int srow = tid >> 3;
    int sq = (tid & 7) ^ (srow & 7);
    const short* gA = (const short*)Xb + (size_t)(m0 + srow) * 256 + sq * 8;
    const short* gB = (const short*)Wob + (size_t)(n0 + srow) * 256 + sq * 8;

    f32x4 acc[4][4] = {};
    const short* pa = sA + (wm * 64 + lcol) * 64;
    const short* pb = sB + (wn * 64 + lcol) * 64;
    int rx7 = lcol & 7;
    int qa0 = (lrow ^ rx7) * 8;
    int qa1 = ((4 + lrow) ^ rx7) * 8;

    uint4 ra[4], rb2[4];
#pragma unroll
    for (int j = 0; j < 4; j++) {
        ra[j]  = *(const uint4*)(gA + j * 32 * 256);
        rb2[j] = *(const uint4*)(gB + j * 32 * 256);
    }
#pragma unroll
    for (int it = 0; it < 4; it++) {
        uint4 na[4], nb[4];
        if (it < 3) {
            const short* qA = gA + (it + 1) * 64;
            const short* qB = gB + (it + 1) * 64;
#pragma unroll
            for (int j = 0; j < 4; j++) {
                na[j] = *(const uint4*)(qA + j * 32 * 256);
                nb[j] = *(const uint4*)(qB + j * 32 * 256);
            }
        }
        __syncthreads();
#pragma unroll
        for (int j = 0; j < 4; j++) {
            *(uint4*)((char*)sA + j * 4096 + tid * 16) = ra[j];
            *(uint4*)((char*)sB + j * 4096 + tid * 16) = rb2[j];
        }
        __syncthreads();
        bf16x8 a[4][2], b[4][2];
#pragma unroll
        for (int i = 0; i < 4; i++) {
            a[i][0] = *(const bf16x8*)(pa + i * 16 * 64 + qa0);
            a[i][1] = *(const bf16x8*)(pa + i * 16 * 64 + qa1);
            b[i][0] = *(const bf16x8*)(pb + i * 16 * 64 + qa0);
            b[i][1] = *(const bf16x8*)(pb + i * 16 * 64 + qa1);
        }
#pragma unroll
        for (int kh = 0; kh < 2; kh++)
#pragma unroll
            for (int mi = 0; mi < 4; mi++)
#pragma unroll
                for (int ni = 0; ni < 4; ni++)
                    acc[mi][ni] = __builtin_amdgcn_mfma_f32_16x16x32_bf16(
                        a[mi][kh], b[ni][kh], acc[mi][ni], 0, 0, 0);
        if (it < 3) {
#pragma unroll
            for (int j = 0; j < 4; j++) { ra[j] = na[j]; rb2[j] = nb[j]; }
        }
    }

#pragma unroll
    for (int mi = 0; mi < 4; mi++) {
#pragma unroll
        for (int ni = 0; ni < 4; ni++) {
            int n = n0 + wn * 64 + ni * 16 + lcol;
            float bn = bias[n];
#pragma unroll
            for (int r = 0; r < 4; r++) {
                int m = m0 + wm * 64 + mi * 16 + lrow * 4 + r;
                Out[(size_t)m * 256 + n] = acc[mi][ni][r] + bn;
            }
        }
    }
}

// ---------------- stage C: softmax + bilinear sampling ----------------
// Block = 4 waves = 4 queries. Gather: lane = (p8=lane>>3, seg=lane&7);
// dwordx2 per lane. s_iw padded to 5 int2/point -> conflict-free broadcasts.
__global__ __launch_bounds__(256) void k_sample(
    const unsigned short* __restrict__ Vtb,  // (4,8,5440,32) bf16
    const float* __restrict__ refp,          // (4,5440,4,2)
    const float* __restrict__ offs,          // (M,128,2)
    const float* __restrict__ awl,           // (M,128)
    unsigned short* __restrict__ atnb)       // (M,256) bf16
{
    int tid = threadIdx.x;
    int m_base = blockIdx.x * 4;
    __shared__ int2 s_iw[4][128][5];   // {byte row offset, weight bits}, padded

    // ---- prep: 512 (mloc,point) pairs on 256 threads, 2 reps ----
#pragma unroll
    for (int rep = 0; rep < 2; rep++) {
        int p = tid & 127;
        int mloc = (tid >> 7) + rep * 2;
        int m = m_base + mloc;
        int l = (p >> 2) & 3;
        float logit = awl[(size_t)m * 128 + p];
        float mx = logit;
#pragma unroll
        for (int off = 1; off < 16; off <<= 1) mx = fmaxf(mx, __shfl_xor(mx, off));
        float e = __expf(logit - mx);
        float s = e;
#pragma unroll
        for (int off = 1; off < 16; off <<= 1) s += __shfl_xor(s, off);
        float prob = e * __builtin_amdgcn_rcpf(s);

        float ox = offs[((size_t)m * 128 + p) * 2 + 0];
        float oy = offs[((size_t)m * 128 + p) * 2 + 1];
        float rx = refp[(size_t)m * 8 + l * 2 + 0];
        float ry = refp[(size_t)m * 8 + l * 2 + 1];
        int Wl = 64 >> l;
        int base = (l == 0) ? 0 : (l == 1) ? 4096 : (l == 2) ? 5120 : 5376;
        float fW = (float)Wl;
        float x = rx * fW + ox - 0.5f;
        float y = ry * fW + oy - 0.5f;
        float x0f = floorf(x), y0f = floorf(y);
        float wx = x - x0f, wy = y - y0f;
        int x0 = (int)x0f, y0 = (int)y0f;
        int xc0 = min(max(x0, 0), Wl - 1), xc1 = min(max(x0 + 1, 0), Wl - 1);
        int yc0 = min(max(y0, 0), Wl - 1), yc1 = min(max(y0 + 1, 0), Wl - 1);
        float vx0 = (x0 >= 0 && x0 < Wl) ? 1.f : 0.f;
        float vx1 = (x0 + 1 < Wl) ? 1.f : 0.f;
        float vy0 = (y0 >= 0 && y0 < Wl) ? 1.f : 0.f;
        float vy1 = (y0 + 1 < Wl) ? 1.f : 0.f;
        if (x0 + 1 < 0) vx1 = 0.f;
        if (y0 + 1 < 0) vy1 = 0.f;
        s_iw[mloc][p][0] = make_int2((base + yc0 * Wl + xc0) * 64,
                                     __float_as_int(prob * (1.f - wx) * (1.f - wy) * vx0 * vy0));
        s_iw[mloc][p][1] = make_int2((base + yc0 * Wl + xc1) * 64,
                                     __float_as_int(prob * wx * (1.f - wy) * vx1 * vy0));
        s_iw[mloc][p][2] = make_int2((base + yc1 * Wl + xc0) * 64,
                                     __float_as_int(prob * (1.f - wx) * wy * vx0 * vy1));
        s_iw[mloc][p][3] = make_int2((base + yc1 * Wl + xc1) * 64,
                                     __float_as_int(prob * wx * wy * vx1 * vy1));
    }
    __syncthreads();

    // ---- gather ----
    int wv = tid >> 6, lane = tid & 63;
    int p8 = lane >> 3, seg = lane & 7;   // seg: 8B = 4 channels
    int m = m_base + wv;
    int b = m / LQ;
    const char* vB = (const char*)(Vtb + (size_t)b * NH * LQ * DH) + seg * 8;
#pragma unroll
    for (int h = 0; h < 8; h++) {
        const char* ph = vB + (size_t)h * (LQ * DH * 2);
        float a0 = 0.f, a1 = 0.f, a2 = 0.f, a3 = 0.f;
#pragma unroll
        for (int pg = 0; pg < 2; pg++) {
            int p = h * 16 + pg * 8 + p8;
#pragma unroll
            for (int c = 0; c < 4; c++) {
                int2 iw = s_iw[wv][p][c];
                uint2 v = *(const uint2*)(ph + iw.x);
                float wgt = __int_as_float(iw.y);
                a0 += wgt * __uint_as_float(v.x << 16);
                a1 += wgt * __uint_as_float(v.x & 0xffff0000u);
                a2 += wgt * __uint_as_float(v.y << 16);
                a3 += wgt * __uint_as_float(v.y & 0xffff0000u);
            }
        }
#pragma unroll
        for (int off = 8; off <= 32; off <<= 1) {
            a0 += __shfl_xor(a0, off);
            a1 += __shfl_xor(a1, off);
            a2 += __shfl_xor(a2, off);
            a3 += __shfl_xor(a3, off);
        }
        if (p8 == 0) {
            ((uint2*)atnb)[(size_t)m * 64 + h * 8 + seg] =
                make_uint2(pk2(a0, a1), pk2(a2, a3));
        }
    }
}

// ---------------- launch ----------------
extern "C" void kernel_launch(void* const* d_in, const int* in_sizes, int n_in,
                              void* d_out, int out_size, void* d_ws, size_t ws_size,
                              hipStream_t stream) {
    const float* query  = (const float*)d_in[0];
    const float* refp   = (const float*)d_in[1];
    const float* inflat = (const float*)d_in[2];
    // d_in[3] = input_spatial_shapes (static, unused)
    const float* We  = (const float*)d_in[4];
    const float* SW  = (const float*)d_in[5];
    const float* SB  = (const float*)d_in[6];
    const float* AWw = (const float*)d_in[7];
    const float* ABb = (const float*)d_in[8];
    const float* VW  = (const float*)d_in[9];
    const float* Vb  = (const float*)d_in[10];
    const float* OW  = (const float*)d_in[11];
    const float* Ob  = (const float*)d_in[12];
    float* out = (float*)d_out;

    float* ws = (float*)d_ws;
    unsigned short* Vtb  = (unsigned short*)ws;                    // 5,570,560 shorts
    float* offs          = ws + 2785280;                           // 5,570,560 f
    float* awl           = offs + 5570560;                         // 2,785,280 f
    unsigned short* Qbf  = (unsigned short*)(awl + 2785280);       // 5,570,560 shorts
    unsigned short* Webf = Qbf + 5570560;                          // 1,048,576 shorts
    unsigned short* Xbf  = Webf + 1048576;                         // 5,570,560 shorts
    unsigned short* Wvbf = Xbf + 5570560;                          // 65,536 shorts
    unsigned short* OWbf = Wvbf + 65536;                           // 65,536 shorts
    unsigned short* Rbf  = OWbf + 65536;                           // 65,536 shorts
    unsigned short* atnb = Xbf;   // alias: Xbf consumed by k_value_mfma before k_sample writes

    k_cvt2<<<dim3(5440, 2), 256, 0, stream>>>(query, Qbf, inflat, Xbf, MTOT * 256 / 4);
    k_cvt3<<<dim3(1024, 4), 256, 0, stream>>>(We, Webf, OEN * 256 / 4,
                                              VW, Wvbf, 256 * 256 / 4,
                                              OW, OWbf, 256 * 256 / 4,
                                              SW, AWw, Rbf);

    k_value_mfma<<<dim3(2, MTOT / 128), 256, 0, stream>>>(Xbf, Wvbf, Vb, Vtb);

    k_oe_mfma<<<dim3(OEN / 128, MTOT / 128), 256, 0, stream>>>(
        Qbf, Webf, Rbf, SB, ABb, offs, awl);

    k_sample<<<dim3(MTOT / 4), 256, 0, stream>>>(Vtb, refp, offs, awl, atnb);

    k_out_mfma<<<dim3(2, MTOT / 128), 256, 0, stream>>>(atnb, OWbf, Ob, out);
}

// Round 8
// 282.821 us; speedup vs baseline: 2.0831x; 2.0831x over previous
//
#include <hip/hip_runtime.h>
#include <hip/hip_bf16.h>

// ---------------- problem constants (static pyramid) ----------------
#define NB 4
#define LQ 5440
#define DM 256
#define NH 8
#define NL 4
#define NP 4
#define OFFD 32
#define DH 32
#define MTOT (NB * LQ)             // 21760
#define OEN (NH * NL * NP * OFFD)  // 4096
#define NGRP (NH * NL * NP)        // 128

typedef __attribute__((ext_vector_type(8))) short bf16x8;
typedef __attribute__((ext_vector_type(4))) float f32x4;
typedef unsigned int u32;

#define GLOAD_LDS16(gp, lp) \
    __builtin_amdgcn_global_load_lds((const __attribute__((address_space(1))) u32*)(gp), \
                                     (__attribute__((address_space(3))) u32*)(lp), 16, 0, 0)

__device__ __forceinline__ float bf2f(unsigned short u) {
    union { unsigned int i; float f; } v; v.i = ((unsigned int)u) << 16; return v.f;
}
// cheap RNE f32->bf16 (no NaN path; all values finite here)
__device__ __forceinline__ unsigned short f2bf(float x) {
    u32 u = __float_as_uint(x);
    u = u + 0x7fffu + ((u >> 16) & 1u);
    return (unsigned short)(u >> 16);
}
__device__ __forceinline__ u32 pk2(float a, float b) {
    u32 ua = __float_as_uint(a), ub = __float_as_uint(b);
    ua = ua + 0x7fffu + ((ua >> 16) & 1u);
    ub = ub + 0x7fffu + ((ub >> 16) & 1u);
    return (ua >> 16) | (ub & 0xffff0000u);
}
__device__ __forceinline__ float silu(float x) {
    float e = __expf(-x);
    return x * __builtin_amdgcn_rcpf(1.0f + e);   // v_rcp_f32, ~1 ulp
}

// ---------------- fp32 -> bf16 conversions ----------------
__global__ __launch_bounds__(256) void k_cvt2(
    const float* __restrict__ A, unsigned short* __restrict__ Ao,
    const float* __restrict__ B, unsigned short* __restrict__ Bo, int n4)
{
    int i = blockIdx.x * 256 + threadIdx.x;
    if (i >= n4) return;
    const float* src = blockIdx.y ? B : A;
    unsigned short* dst = blockIdx.y ? Bo : Ao;
    float4 v = *(const float4*)(src + (size_t)i * 4);
    ushort4 o;
    o.x = f2bf(v.x); o.y = f2bf(v.y); o.z = f2bf(v.z); o.w = f2bf(v.w);
    *(ushort4*)(dst + (size_t)i * 4) = o;
}
// weight tensors + Rb prepack (y==3)
__global__ __launch_bounds__(256) void k_cvt3(
    const float* __restrict__ A, unsigned short* __restrict__ Ao, int nA4,
    const float* __restrict__ B, unsigned short* __restrict__ Bo, int nB4,
    const float* __restrict__ C, unsigned short* __restrict__ Co, int nC4,
    const float* __restrict__ SW, const float* __restrict__ AW,
    unsigned short* __restrict__ Rb)
{
    int i = blockIdx.x * 256 + threadIdx.x;
    if (blockIdx.y == 3) {
        if (i < 65536) {
            int gg = i >> 9, jo = (i >> 5) & 15, d = i & 31;
            float v = 0.f;
            if (jo == 0)      v = SW[(gg * 32 + d) * 2 + 0];
            else if (jo == 1) v = SW[(gg * 32 + d) * 2 + 1];
            else if (jo == 2) v = AW[gg * 32 + d];
            Rb[i] = f2bf(v);
        }
        return;
    }
    const float* src; unsigned short* dst; int n4;
    if (blockIdx.y == 0)      { src = A; dst = Ao; n4 = nA4; }
    else if (blockIdx.y == 1) { src = B; dst = Bo; n4 = nB4; }
    else                      { src = C; dst = Co; n4 = nC4; }
    if (i >= n4) return;
    float4 v = *(const float4*)(src + (size_t)i * 4);
    ushort4 o;
    o.x = f2bf(v.x); o.y = f2bf(v.y); o.z = f2bf(v.z); o.w = f2bf(v.w);
    *(ushort4*)(dst + (size_t)i * 4) = o;
}

// ============================================================================
// MFMA GEMM skeleton (round-6 verified): 128x128 tile, BK=64, XOR-swizzled
// global_load_lds staging. Register-prefetch variant REVERTED (round 7:
// scratch spills, WRITE_SIZE 51MB -> 1.2GB).
// LDS slot (row=c>>3, q=c&7) holds GLOBAL chunk (row, q ^ (row&7)).
// C/D layout (verified): col = lane&15, row = (lane>>4)*4 + reg.
// ============================================================================

// ---------------- stage B: oe GEMM (A=We, B=Q) + silu + MFMA reduction ------
__global__ __launch_bounds__(256) void k_oe_mfma(
    const unsigned short* __restrict__ Qb,   // (21760,256) bf16
    const unsigned short* __restrict__ Wb,   // (4096,256) bf16
    const unsigned short* __restrict__ Rb,   // (128,16,32) bf16 reduction frags
    const float* __restrict__ SB,    // (128,2)
    const float* __restrict__ AB,    // (128)
    float* __restrict__ offs_out,    // (M,128,2)
    float* __restrict__ aw_out)      // (M,128)
{
    __shared__ short sA[128 * 64];   // Q rows
    __shared__ short sB[128 * 64];   // We rows
    int tid = threadIdx.x;
    int n0 = blockIdx.x * 128;   // We/n fastest-varying -> blocks share Q via L2
    int m0 = blockIdx.y * 128;

    int lane = tid & 63;
    int w = tid >> 6;
    int wA = w >> 1;            // We half (mfma-m)
    int wB = w & 1;             // Q half (mfma-n)
    int lcol = lane & 15, quad = lane >> 4;

    int srow = tid >> 3;
    int sq = (tid & 7) ^ (srow & 7);
    const short* gA = (const short*)Qb + (size_t)(m0 + srow) * 256 + sq * 8;
    const short* gB = (const short*)Wb + (size_t)(n0 + srow) * 256 + sq * 8;
    short* lA = sA + w * 512;
    short* lB = sB + w * 512;

    f32x4 acc[4][4] = {};   // [We-tile i][Q-tile j]

    const short* pq = sA + (wB * 64 + lcol) * 64;   // Q fragments (B operand)
    const short* pw = sB + (wA * 64 + lcol) * 64;   // We fragments (A operand)
    int rx7 = lcol & 7;
    int qa0 = (quad ^ rx7) * 8;
    int qa1 = ((4 + quad) ^ rx7) * 8;

    for (int kc = 0; kc < 256; kc += 64) {
#pragma unroll
        for (int j = 0; j < 4; j++) {
            GLOAD_LDS16(gA + kc + j * 32 * 256, lA + j * 2048);
            GLOAD_LDS16(gB + kc + j * 32 * 256, lB + j * 2048);
        }
        __syncthreads();
        bf16x8 a[4][2], b[4][2];
#pragma unroll
        for (int i = 0; i < 4; i++) {
            a[i][0] = *(const bf16x8*)(pw + i * 16 * 64 + qa0);  // We
            a[i][1] = *(const bf16x8*)(pw + i * 16 * 64 + qa1);
            b[i][0] = *(const bf16x8*)(pq + i * 16 * 64 + qa0);  // Q
            b[i][1] = *(const bf16x8*)(pq + i * 16 * 64 + qa1);
        }
#pragma unroll
        for (int kh = 0; kh < 2; kh++)
#pragma unroll
            for (int i = 0; i < 4; i++)
#pragma unroll
                for (int j = 0; j < 4; j++)
                    acc[i][j] = __builtin_amdgcn_mfma_f32_16x16x32_bf16(
                        a[i][kh], b[j][kh], acc[i][j], 0, 0, 0);
        __syncthreads();
    }

    // ---- epilogue: silu -> bf16 pack (registers) -> MFMA reduction ----
    u32 ps[4][4][2];
#pragma unroll
    for (int i = 0; i < 4; i++)
#pragma unroll
        for (int j = 0; j < 4; j++) {
            ps[i][j][0] = pk2(silu(acc[i][j][0]), silu(acc[i][j][1]));
            ps[i][j][1] = pk2(silu(acc[i][j][2]), silu(acc[i][j][3]));
        }

    int srcbase = (quad & 1) * 32 + lcol;
    bool hi = quad >= 2;
    f32x4 zero = {};
#pragma unroll
    for (int g = 0; g < 2; g++) {
        int gg = (n0 + wA * 64 + g * 32) >> 5;
        bf16x8 afrag = *(const bf16x8*)(Rb + ((size_t)(gg * 16 + lcol) * 32 + quad * 8));
        float sb0 = SB[gg * 2 + 0], sb1 = SB[gg * 2 + 1], ab = AB[gg];
#pragma unroll
        for (int j = 0; j < 4; j++) {
            union { u32 u[4]; bf16x8 v; } bf;
#pragma unroll
            for (int b = 0; b < 2; b++) {
                int s = srcbase + b * 16;
#pragma unroll
                for (int c = 0; c < 2; c++) {
                    u32 x0 = (u32)__shfl((int)ps[2 * g + 0][j][c], s);
                    u32 x1 = (u32)__shfl((int)ps[2 * g + 1][j][c], s);
                    bf.u[b * 2 + c] = hi ? x1 : x0;
                }
            }
            f32x4 d2 = __builtin_amdgcn_mfma_f32_16x16x32_bf16(afrag, bf.v, zero, 0, 0, 0);
            if (quad == 0) {
                int m = m0 + wB * 64 + j * 16 + lcol;
                size_t oi = ((size_t)m * NGRP + gg) * 2;
                offs_out[oi + 0] = d2[0] + sb0;
                offs_out[oi + 1] = d2[1] + sb1;
                aw_out[(size_t)m * NGRP + gg] = d2[2] + ab;
            }
        }
    }
}

// ---------------- stage A: value projection (swapped operands) ----------------
__global__ __launch_bounds__(256) void k_value_mfma(
    const unsigned short* __restrict__ Xb,   // (21760,256) bf16
    const unsigned short* __restrict__ Wvb,  // (256,256) bf16 (n,k)
    const float* __restrict__ bias,          // (256)
    unsigned short* __restrict__ Vtb)        // (4,8,5440,32) bf16
{
    __shared__ short sA[128 * 64];   // X rows
    __shared__ short sB[128 * 64];   // Wv rows
    int tid = threadIdx.x;
    int n0 = blockIdx.x * 128;
    int m0 = blockIdx.y * 128;
    int lane = tid & 63;
    int w = tid >> 6;
    int wA = w >> 1;            // Wv half (mfma-m)
    int wB = w & 1;             // X half (mfma-n)
    int lcol = lane & 15, quad = lane >> 4;

    int srow = tid >> 3;
    int sq = (tid & 7) ^ (srow & 7);
    const short* gA = (const short*)Xb + (size_t)(m0 + srow) * 256 + sq * 8;
    const short* gB = (const short*)Wvb + (size_t)(n0 + srow) * 256 + sq * 8;
    short* lA = sA + w * 512;
    short* lB = sB + w * 512;

    f32x4 acc[4][4] = {};   // [Wv-tile i][X-tile j]
    const short* px = sA + (wB * 64 + lcol) * 64;
    const short* pw = sB + (wA * 64 + lcol) * 64;
    int rx7 = lcol & 7;
    int qa0 = (quad ^ rx7) * 8;
    int qa1 = ((4 + quad) ^ rx7) * 8;

    for (int kc = 0; kc < 256; kc += 64) {
#pragma unroll
        for (int j = 0; j < 4; j++) {
            GLOAD_LDS16(gA + kc + j * 32 * 256, lA + j * 2048);
            GLOAD_LDS16(gB + kc + j * 32 * 256, lB + j * 2048);
        }
        __syncthreads();
        bf16x8 a[4][2], b[4][2];
#pragma unroll
        for (int i = 0; i < 4; i++) {
            a[i][0] = *(const bf16x8*)(pw + i * 16 * 64 + qa0);  // Wv
            a[i][1] = *(const bf16x8*)(pw + i * 16 * 64 + qa1);
            b[i][0] = *(const bf16x8*)(px + i * 16 * 64 + qa0);  // X
            b[i][1] = *(const bf16x8*)(px + i * 16 * 64 + qa1);
        }
#pragma unroll
        for (int kh = 0; kh < 2; kh++)
#pragma unroll
            for (int i = 0; i < 4; i++)
#pragma unroll
                for (int j = 0; j < 4; j++)
                    acc[i][j] = __builtin_amdgcn_mfma_f32_16x16x32_bf16(
                        a[i][kh], b[j][kh], acc[i][j], 0, 0, 0);
        __syncthreads();
    }

#pragma unroll
    for (int i = 0; i < 4; i++) {
        int nb4 = n0 + wA * 64 + i * 16 + quad * 4;   // 4 consecutive n
        int h = nb4 >> 5, db = nb4 & 31;
        float4 b4 = *(const float4*)&bias[nb4];
#pragma unroll
        for (int j = 0; j < 4; j++) {
            int m = m0 + wB * 64 + j * 16 + lcol;
            int b = m / LQ, q = m - b * LQ;
            u32 lo = pk2(acc[i][j][0] + b4.x, acc[i][j][1] + b4.y);
            u32 hi2 = pk2(acc[i][j][2] + b4.z, acc[i][j][3] + b4.w);
            char* dst = (char*)Vtb + ((((size_t)b * NH + h) * LQ + q) * DH + db) * 2;
            *(uint2*)dst = make_uint2(lo, hi2);
        }
    }
}

// ---------------- stage D: output projection ----------------
__global__ __launch_bounds__(256) void k_out_mfma(
    const unsigned short* __restrict__ Xb,   // (21760,256) bf16 attn
    const unsigned short* __restrict__ Wob,  // (256,256) bf16 (n,k)
    const float* __restrict__ bias,          // (256)
    float* __restrict__ Out)                 // (21760,256) fp32
{
    __shared__ short sA[128 * 64];
    __shared__ short sB[128 * 64];
    int tid = threadIdx.x;
    int n0 = blockIdx.x * 128;
    int m0 = blockIdx.y * 128;
    int lane = tid & 63;
    int w = tid >> 6;
    int wm = w >> 1, wn = w & 1;
    int lcol = lane & 15, lrow = lane >> 4;

    int srow = tid >> 3;
    int sq = (tid & 7) ^ (srow & 7);
    const short* gA = (const short*)Xb + (size_t)(m0 + srow) * 256 + sq * 8;
    const short* gB = (const short*)Wob + (size_t)(n0 + srow) * 256 + sq * 8;
    short* lA = sA + w * 512;
    short* lB = sB + w * 512;

    f32x4 acc[4][4] = {};
    const short* pa = sA + (wm * 64 + lcol) * 64;
    const short* pb = sB + (wn * 64 + lcol) * 64;
    int rx7 = lcol & 7;
    int qa0 = (lrow ^ rx7) * 8;
    int qa1 = ((4 + lrow) ^ rx7) * 8;

    for (int kc = 0; kc < 256; kc += 64) {
#pragma unroll
        for (int j = 0; j < 4; j++) {
            GLOAD_LDS16(gA + kc + j * 32 * 256, lA + j * 2048);
            GLOAD_LDS16(gB + kc + j * 32 * 256, lB + j * 2048);
        }
        __syncthreads();
        bf16x8 a[4][2], b[4][2];
#pragma unroll
        for (int i = 0; i < 4; i++) {
            a[i][0] = *(const bf16x8*)(pa + i * 16 * 64 + qa0);
            a[i][1] = *(const bf16x8*)(pa + i * 16 * 64 + qa1);
            b[i][0] = *(const bf16x8*)(pb + i * 16 * 64 + qa0);
            b[i][1] = *(const bf16x8*)(pb + i * 16 * 64 + qa1);
        }
#pragma unroll
        for (int kh = 0; kh < 2; kh++)
#pragma unroll
            for (int mi = 0; mi < 4; mi++)
#pragma unroll
                for (int ni = 0; ni < 4; ni++)
                    acc[mi][ni] = __builtin_amdgcn_mfma_f32_16x16x32_bf16(
                        a[mi][kh], b[ni][kh], acc[mi][ni], 0, 0, 0);
        __syncthreads();
    }

#pragma unroll
    for (int mi = 0; mi < 4; mi++) {
#pragma unroll
        for (int ni = 0; ni < 4; ni++) {
            int n = n0 + wn * 64 + ni * 16 + lcol;
            float bn = bias[n];
#pragma unroll
            for (int r = 0; r < 4; r++) {
                int m = m0 + wm * 64 + mi * 16 + lrow * 4 + r;
                Out[(size_t)m * 256 + n] = acc[mi][ni][r] + bn;
            }
        }
    }
}

// ---------------- stage C: softmax + bilinear sampling, per-head blocks -----
// Block = 4 waves = 4 queries x ONE head. Grid (MTOT/4, NH), head slowest ->
// co-resident blocks share one 1.4 MB (b,h) value plane -> per-XCD L2 hits.
// Wave-local prep (lanes 0..15 = the head's 16 points); gather lane =
// (p8=lane>>3, seg=lane&7), dwordx2; corners in-register; 3-round reduce.
__global__ __launch_bounds__(256) void k_sample(
    const unsigned short* __restrict__ Vtb,  // (4,8,5440,32) bf16
    const float* __restrict__ refp,          // (4,5440,4,2)
    const float* __restrict__ offs,          // (M,128,2)
    const float* __restrict__ awl,           // (M,128)
    unsigned short* __restrict__ atnb)       // (M,256) bf16
{
    int tid = threadIdx.x;
    int h = blockIdx.y;
    int m_base = blockIdx.x * 4;
    int wv = tid >> 6, lane = tid & 63;
    int m = m_base + wv;
    __shared__ int2 s_iw[4][16][5];   // per wave: 16 points x 4 corners (padded)

    if (lane < 16) {
        int idx16 = lane;               // point within this head
        int p = h * 16 + idx16;
        int l = idx16 >> 2;             // level
        float logit = awl[(size_t)m * 128 + p];
        float mx = logit;
#pragma unroll
        for (int off = 1; off < 16; off <<= 1) mx = fmaxf(mx, __shfl_xor(mx, off));
        float e = __expf(logit - mx);
        float s = e;
#pragma unroll
        for (int off = 1; off < 16; off <<= 1) s += __shfl_xor(s, off);
        float prob = e * __builtin_amdgcn_rcpf(s);

        float ox = offs[((size_t)m * 128 + p) * 2 + 0];
        float oy = offs[((size_t)m * 128 + p) * 2 + 1];
        float rx = refp[(size_t)m * 8 + l * 2 + 0];
        float ry = refp[(size_t)m * 8 + l * 2 + 1];
        int Wl = 64 >> l;
        int base = (l == 0) ? 0 : (l == 1) ? 4096 : (l == 2) ? 5120 : 5376;
        float fW = (float)Wl;
        float x = rx * fW + ox - 0.5f;
        float y = ry * fW + oy - 0.5f;
        float x0f = floorf(x), y0f = floorf(y);
        float wx = x - x0f, wy = y - y0f;
        int x0 = (int)x0f, y0 = (int)y0f;
        int xc0 = min(max(x0, 0), Wl - 1), xc1 = min(max(x0 + 1, 0), Wl - 1);
        int yc0 = min(max(y0, 0), Wl - 1), yc1 = min(max(y0 + 1, 0), Wl - 1);
        float vx0 = (x0 >= 0 && x0 < Wl) ? 1.f : 0.f;
        float vx1 = (x0 + 1 >= 0 && x0 + 1 < Wl) ? 1.f : 0.f;
        float vy0 = (y0 >= 0 && y0 < Wl) ? 1.f : 0.f;
        float vy1 = (y0 + 1 >= 0 && y0 + 1 < Wl) ? 1.f : 0.f;
        s_iw[wv][idx16][0] = make_int2((base + yc0 * Wl + xc0) * 64,
                                       __float_as_int(prob * (1.f - wx) * (1.f - wy) * vx0 * vy0));
        s_iw[wv][idx16][1] = make_int2((base + yc0 * Wl + xc1) * 64,
                                       __float_as_int(prob * wx * (1.f - wy) * vx1 * vy0));
        s_iw[wv][idx16][2] = make_int2((base + yc1 * Wl + xc0) * 64,
                                       __float_as_int(prob * (1.f - wx) * wy * vx0 * vy1));
        s_iw[wv][idx16][3] = make_int2((base + yc1 * Wl + xc1) * 64,
                                       __float_as_int(prob * wx * wy * vx1 * vy1));
    }
    __syncthreads();

    int p8 = lane >> 3, seg = lane & 7;   // seg: 8B = 4 channels
    int b = m / LQ;
    const char* ph = (const char*)(Vtb + ((size_t)b * NH + h) * LQ * DH) + seg * 8;
    float a0 = 0.f, a1 = 0.f, a2 = 0.f, a3 = 0.f;
#pragma unroll
    for (int pg = 0; pg < 2; pg++) {
        int pt = pg * 8 + p8;
#pragma unroll
        for (int c = 0; c < 4; c++) {
            int2 iw = s_iw[wv][pt][c];
            uint2 v = *(const uint2*)(ph + iw.x);
            float wgt = __int_as_float(iw.y);
            a0 += wgt * __uint_as_float(v.x << 16);
            a1 += wgt * __uint_as_float(v.x & 0xffff0000u);
            a2 += wgt * __uint_as_float(v.y << 16);
            a3 += wgt * __uint_as_float(v.y & 0xffff0000u);
        }
    }
#pragma unroll
    for (int off = 8; off <= 32; off <<= 1) {
        a0 += __shfl_xor(a0, off);
        a1 += __shfl_xor(a1, off);
        a2 += __shfl_xor(a2, off);
        a3 += __shfl_xor(a3, off);
    }
    if (p8 == 0) {
        ((uint2*)atnb)[(size_t)m * 64 + h * 8 + seg] =
            make_uint2(pk2(a0, a1), pk2(a2, a3));
    }
}

// ---------------- launch ----------------
extern "C" void kernel_launch(void* const* d_in, const int* in_sizes, int n_in,
                              void* d_out, int out_size, void* d_ws, size_t ws_size,
                              hipStream_t stream) {
    const float* query  = (const float*)d_in[0];
    const float* refp   = (const float*)d_in[1];
    const float* inflat = (const float*)d_in[2];
    // d_in[3] = input_spatial_shapes (static, unused)
    const float* We  = (const float*)d_in[4];
    const float* SW  = (const float*)d_in[5];
    const float* SB  = (const float*)d_in[6];
    const float* AWw = (const float*)d_in[7];
    const float* ABb = (const float*)d_in[8];
    const float* VW  = (const float*)d_in[9];
    const float* Vb  = (const float*)d_in[10];
    const float* OW  = (const float*)d_in[11];
    const float* Ob  = (const float*)d_in[12];
    float* out = (float*)d_out;

    float* ws = (float*)d_ws;
    unsigned short* Vtb  = (unsigned short*)ws;                    // 5,570,560 shorts
    float* offs          = ws + 2785280;                           // 5,570,560 f
    float* awl           = offs + 5570560;                         // 2,785,280 f
    unsigned short* Qbf  = (unsigned short*)(awl + 2785280);       // 5,570,560 shorts
    unsigned short* Webf = Qbf + 5570560;                          // 1,048,576 shorts
    unsigned short* Xbf  = Webf + 1048576;                         // 5,570,560 shorts
    unsigned short* Wvbf = Xbf + 5570560;                          // 65,536 shorts
    unsigned short* OWbf = Wvbf + 65536;                           // 65,536 shorts
    unsigned short* Rbf  = OWbf + 65536;                           // 65,536 shorts
    unsigned short* atnb = Xbf;   // alias: Xbf consumed by k_value_mfma before k_sample writes

    k_cvt2<<<dim3(5440, 2), 256, 0, stream>>>(query, Qbf, inflat, Xbf, MTOT * 256 / 4);
    k_cvt3<<<dim3(1024, 4), 256, 0, stream>>>(We, Webf, OEN * 256 / 4,
                                              VW, Wvbf, 256 * 256 / 4,
                                              OW, OWbf, 256 * 256 / 4,
                                              SW, AWw, Rbf);

    k_value_mfma<<<dim3(2, MTOT / 128), 256, 0, stream>>>(Xbf, Wvbf, Vb, Vtb);

    k_oe_mfma<<<dim3(OEN / 128, MTOT / 128), 256, 0, stream>>>(
        Qbf, Webf, Rbf, SB, ABb, offs, awl);

    k_sample<<<dim3(MTOT / 4, NH), 256, 0, stream>>>(Vtb, refp, offs, awl, atnb);

    k_out_mfma<<<dim3(2, MTOT / 128), 256, 0, stream>>>(atnb, OWbf, Ob, out);
}

// Round 9
// 245.232 us; speedup vs baseline: 2.4024x; 1.1533x over previous
//
#include <hip/hip_runtime.h>
#include <hip/hip_bf16.h>

// ---------------- problem constants (static pyramid) ----------------
#define NB 4
#define LQ 5440
#define DM 256
#define NH 8
#define NL 4
#define NP 4
#define OFFD 32
#define DH 32
#define MTOT (NB * LQ)             // 21760
#define OEN (NH * NL * NP * OFFD)  // 4096
#define NGRP (NH * NL * NP)        // 128

typedef __attribute__((ext_vector_type(8))) short bf16x8;
typedef __attribute__((ext_vector_type(4))) float f32x4;
typedef unsigned int u32;

#define GLOAD_LDS16(gp, lp) \
    __builtin_amdgcn_global_load_lds((const __attribute__((address_space(1))) u32*)(gp), \
                                     (__attribute__((address_space(3))) u32*)(lp), 16, 0, 0)

__device__ __forceinline__ float bf2f(unsigned short u) {
    union { unsigned int i; float f; } v; v.i = ((unsigned int)u) << 16; return v.f;
}
// cheap RNE f32->bf16 (no NaN path; all values finite here)
__device__ __forceinline__ unsigned short f2bf(float x) {
    u32 u = __float_as_uint(x);
    u = u + 0x7fffu + ((u >> 16) & 1u);
    return (unsigned short)(u >> 16);
}
__device__ __forceinline__ u32 pk2(float a, float b) {
    u32 ua = __float_as_uint(a), ub = __float_as_uint(b);
    ua = ua + 0x7fffu + ((ua >> 16) & 1u);
    ub = ub + 0x7fffu + ((ub >> 16) & 1u);
    return (ua >> 16) | (ub & 0xffff0000u);
}
__device__ __forceinline__ float silu(float x) {
    float e = __expf(-x);
    return x * __builtin_amdgcn_rcpf(1.0f + e);   // v_rcp_f32, ~1 ulp
}

// ---------------- fp32 -> bf16 conversions ----------------
__global__ __launch_bounds__(256) void k_cvt2(
    const float* __restrict__ A, unsigned short* __restrict__ Ao,
    const float* __restrict__ B, unsigned short* __restrict__ Bo, int n4)
{
    int i = blockIdx.x * 256 + threadIdx.x;
    if (i >= n4) return;
    const float* src = blockIdx.y ? B : A;
    unsigned short* dst = blockIdx.y ? Bo : Ao;
    float4 v = *(const float4*)(src + (size_t)i * 4);
    ushort4 o;
    o.x = f2bf(v.x); o.y = f2bf(v.y); o.z = f2bf(v.z); o.w = f2bf(v.w);
    *(ushort4*)(dst + (size_t)i * 4) = o;
}
// weight tensors + Rb prepack (y==3)
__global__ __launch_bounds__(256) void k_cvt3(
    const float* __restrict__ A, unsigned short* __restrict__ Ao, int nA4,
    const float* __restrict__ B, unsigned short* __restrict__ Bo, int nB4,
    const float* __restrict__ C, unsigned short* __restrict__ Co, int nC4,
    const float* __restrict__ SW, const float* __restrict__ AW,
    unsigned short* __restrict__ Rb)
{
    int i = blockIdx.x * 256 + threadIdx.x;
    if (blockIdx.y == 3) {
        if (i < 65536) {
            int gg = i >> 9, jo = (i >> 5) & 15, d = i & 31;
            float v = 0.f;
            if (jo == 0)      v = SW[(gg * 32 + d) * 2 + 0];
            else if (jo == 1) v = SW[(gg * 32 + d) * 2 + 1];
            else if (jo == 2) v = AW[gg * 32 + d];
            Rb[i] = f2bf(v);
        }
        return;
    }
    const float* src; unsigned short* dst; int n4;
    if (blockIdx.y == 0)      { src = A; dst = Ao; n4 = nA4; }
    else if (blockIdx.y == 1) { src = B; dst = Bo; n4 = nB4; }
    else                      { src = C; dst = Co; n4 = nC4; }
    if (i >= n4) return;
    float4 v = *(const float4*)(src + (size_t)i * 4);
    ushort4 o;
    o.x = f2bf(v.x); o.y = f2bf(v.y); o.z = f2bf(v.z); o.w = f2bf(v.w);
    *(ushort4*)(dst + (size_t)i * 4) = o;
}

// ============================================================================
// MFMA GEMM skeleton (round-6 verified): 128x128 tile, BK=64, XOR-swizzled
// global_load_lds staging. (Register-prefetch REVERTED: round-7 scratch spill.)
// LDS slot (row=c>>3, q=c&7) holds GLOBAL chunk (row, q ^ (row&7)).
// C/D layout (verified): col = lane&15, row = (lane>>4)*4 + reg.
// ============================================================================

// ---------------- stage B: oe GEMM (A=We, B=Q) + silu + MFMA reduction ------
__global__ __launch_bounds__(256) void k_oe_mfma(
    const unsigned short* __restrict__ Qb,   // (21760,256) bf16
    const unsigned short* __restrict__ Wb,   // (4096,256) bf16
    const unsigned short* __restrict__ Rb,   // (128,16,32) bf16 reduction frags
    const float* __restrict__ SB,    // (128,2)
    const float* __restrict__ AB,    // (128)
    float* __restrict__ offs_out,    // (M,128,2)
    float* __restrict__ aw_out)      // (M,128)
{
    __shared__ short sA[128 * 64];   // Q rows
    __shared__ short sB[128 * 64];   // We rows
    int tid = threadIdx.x;
    int n0 = blockIdx.x * 128;   // We/n fastest-varying -> blocks share Q via L2
    int m0 = blockIdx.y * 128;

    int lane = tid & 63;
    int w = tid >> 6;
    int wA = w >> 1;            // We half (mfma-m)
    int wB = w & 1;             // Q half (mfma-n)
    int lcol = lane & 15, quad = lane >> 4;

    int srow = tid >> 3;
    int sq = (tid & 7) ^ (srow & 7);
    const short* gA = (const short*)Qb + (size_t)(m0 + srow) * 256 + sq * 8;
    const short* gB = (const short*)Wb + (size_t)(n0 + srow) * 256 + sq * 8;
    short* lA = sA + w * 512;
    short* lB = sB + w * 512;

    f32x4 acc[4][4] = {};   // [We-tile i][Q-tile j]

    const short* pq = sA + (wB * 64 + lcol) * 64;   // Q fragments (B operand)
    const short* pw = sB + (wA * 64 + lcol) * 64;   // We fragments (A operand)
    int rx7 = lcol & 7;
    int qa0 = (quad ^ rx7) * 8;
    int qa1 = ((4 + quad) ^ rx7) * 8;

    for (int kc = 0; kc < 256; kc += 64) {
#pragma unroll
        for (int j = 0; j < 4; j++) {
            GLOAD_LDS16(gA + kc + j * 32 * 256, lA + j * 2048);
            GLOAD_LDS16(gB + kc + j * 32 * 256, lB + j * 2048);
        }
        __syncthreads();
        bf16x8 a[4][2], b[4][2];
#pragma unroll
        for (int i = 0; i < 4; i++) {
            a[i][0] = *(const bf16x8*)(pw + i * 16 * 64 + qa0);  // We
            a[i][1] = *(const bf16x8*)(pw + i * 16 * 64 + qa1);
            b[i][0] = *(const bf16x8*)(pq + i * 16 * 64 + qa0);  // Q
            b[i][1] = *(const bf16x8*)(pq + i * 16 * 64 + qa1);
        }
#pragma unroll
        for (int kh = 0; kh < 2; kh++)
#pragma unroll
            for (int i = 0; i < 4; i++)
#pragma unroll
                for (int j = 0; j < 4; j++)
                    acc[i][j] = __builtin_amdgcn_mfma_f32_16x16x32_bf16(
                        a[i][kh], b[j][kh], acc[i][j], 0, 0, 0);
        __syncthreads();
    }

    // ---- epilogue: silu -> bf16 pack (registers) -> MFMA reduction ----
    u32 ps[4][4][2];
#pragma unroll
    for (int i = 0; i < 4; i++)
#pragma unroll
        for (int j = 0; j < 4; j++) {
            ps[i][j][0] = pk2(silu(acc[i][j][0]), silu(acc[i][j][1]));
            ps[i][j][1] = pk2(silu(acc[i][j][2]), silu(acc[i][j][3]));
        }

    int srcbase = (quad & 1) * 32 + lcol;
    bool hi = quad >= 2;
    f32x4 zero = {};
#pragma unroll
    for (int g = 0; g < 2; g++) {
        int gg = (n0 + wA * 64 + g * 32) >> 5;
        bf16x8 afrag = *(const bf16x8*)(Rb + ((size_t)(gg * 16 + lcol) * 32 + quad * 8));
        float sb0 = SB[gg * 2 + 0], sb1 = SB[gg * 2 + 1], ab = AB[gg];
#pragma unroll
        for (int j = 0; j < 4; j++) {
            union { u32 u[4]; bf16x8 v; } bf;
#pragma unroll
            for (int b = 0; b < 2; b++) {
                int s = srcbase + b * 16;
#pragma unroll
                for (int c = 0; c < 2; c++) {
                    u32 x0 = (u32)__shfl((int)ps[2 * g + 0][j][c], s);
                    u32 x1 = (u32)__shfl((int)ps[2 * g + 1][j][c], s);
                    bf.u[b * 2 + c] = hi ? x1 : x0;
                }
            }
            f32x4 d2 = __builtin_amdgcn_mfma_f32_16x16x32_bf16(afrag, bf.v, zero, 0, 0, 0);
            if (quad == 0) {
                int m = m0 + wB * 64 + j * 16 + lcol;
                size_t oi = ((size_t)m * NGRP + gg) * 2;
                offs_out[oi + 0] = d2[0] + sb0;
                offs_out[oi + 1] = d2[1] + sb1;
                aw_out[(size_t)m * NGRP + gg] = d2[2] + ab;
            }
        }
    }
}

// ---------------- stage A: value projection (swapped operands) ----------------
__global__ __launch_bounds__(256) void k_value_mfma(
    const unsigned short* __restrict__ Xb,   // (21760,256) bf16
    const unsigned short* __restrict__ Wvb,  // (256,256) bf16 (n,k)
    const float* __restrict__ bias,          // (256)
    unsigned short* __restrict__ Vtb)        // (4,8,5440,32) bf16
{
    __shared__ short sA[128 * 64];   // X rows
    __shared__ short sB[128 * 64];   // Wv rows
    int tid = threadIdx.x;
    int n0 = blockIdx.x * 128;
    int m0 = blockIdx.y * 128;
    int lane = tid & 63;
    int w = tid >> 6;
    int wA = w >> 1;            // Wv half (mfma-m)
    int wB = w & 1;             // X half (mfma-n)
    int lcol = lane & 15, quad = lane >> 4;

    int srow = tid >> 3;
    int sq = (tid & 7) ^ (srow & 7);
    const short* gA = (const short*)Xb + (size_t)(m0 + srow) * 256 + sq * 8;
    const short* gB = (const short*)Wvb + (size_t)(n0 + srow) * 256 + sq * 8;
    short* lA = sA + w * 512;
    short* lB = sB + w * 512;

    f32x4 acc[4][4] = {};   // [Wv-tile i][X-tile j]
    const short* px = sA + (wB * 64 + lcol) * 64;
    const short* pw = sB + (wA * 64 + lcol) * 64;
    int rx7 = lcol & 7;
    int qa0 = (quad ^ rx7) * 8;
    int qa1 = ((4 + quad) ^ rx7) * 8;

    for (int kc = 0; kc < 256; kc += 64) {
#pragma unroll
        for (int j = 0; j < 4; j++) {
            GLOAD_LDS16(gA + kc + j * 32 * 256, lA + j * 2048);
            GLOAD_LDS16(gB + kc + j * 32 * 256, lB + j * 2048);
        }
        __syncthreads();
        bf16x8 a[4][2], b[4][2];
#pragma unroll
        for (int i = 0; i < 4; i++) {
            a[i][0] = *(const bf16x8*)(pw + i * 16 * 64 + qa0);  // Wv
            a[i][1] = *(const bf16x8*)(pw + i * 16 * 64 + qa1);
            b[i][0] = *(const bf16x8*)(px + i * 16 * 64 + qa0);  // X
            b[i][1] = *(const bf16x8*)(px + i * 16 * 64 + qa1);
        }
#pragma unroll
        for (int kh = 0; kh < 2; kh++)
#pragma unroll
            for (int i = 0; i < 4; i++)
#pragma unroll
                for (int j = 0; j < 4; j++)
                    acc[i][j] = __builtin_amdgcn_mfma_f32_16x16x32_bf16(
                        a[i][kh], b[j][kh], acc[i][j], 0, 0, 0);
        __syncthreads();
    }

#pragma unroll
    for (int i = 0; i < 4; i++) {
        int nb4 = n0 + wA * 64 + i * 16 + quad * 4;   // 4 consecutive n
        int h = nb4 >> 5, db = nb4 & 31;
        float4 b4 = *(const float4*)&bias[nb4];
#pragma unroll
        for (int j = 0; j < 4; j++) {
            int m = m0 + wB * 64 + j * 16 + lcol;
            int b = m / LQ, q = m - b * LQ;
            u32 lo = pk2(acc[i][j][0] + b4.x, acc[i][j][1] + b4.y);
            u32 hi2 = pk2(acc[i][j][2] + b4.z, acc[i][j][3] + b4.w);
            char* dst = (char*)Vtb + ((((size_t)b * NH + h) * LQ + q) * DH + db) * 2;
            *(uint2*)dst = make_uint2(lo, hi2);
        }
    }
}

// ---------------- stage D: output projection ----------------
__global__ __launch_bounds__(256) void k_out_mfma(
    const unsigned short* __restrict__ Xb,   // (21760,256) bf16 attn
    const unsigned short* __restrict__ Wob,  // (256,256) bf16 (n,k)
    const float* __restrict__ bias,          // (256)
    float* __restrict__ Out)                 // (21760,256) fp32
{
    __shared__ short sA[128 * 64];
    __shared__ short sB[128 * 64];
    int tid = threadIdx.x;
    int n0 = blockIdx.x * 128;
    int m0 = blockIdx.y * 128;
    int lane = tid & 63;
    int w = tid >> 6;
    int wm = w >> 1, wn = w & 1;
    int lcol = lane & 15, lrow = lane >> 4;

    int srow = tid >> 3;
    int sq = (tid & 7) ^ (srow & 7);
    const short* gA = (const short*)Xb + (size_t)(m0 + srow) * 256 + sq * 8;
    const short* gB = (const short*)Wob + (size_t)(n0 + srow) * 256 + sq * 8;
    short* lA = sA + w * 512;
    short* lB = sB + w * 512;

    f32x4 acc[4][4] = {};
    const short* pa = sA + (wm * 64 + lcol) * 64;
    const short* pb = sB + (wn * 64 + lcol) * 64;
    int rx7 = lcol & 7;
    int qa0 = (lrow ^ rx7) * 8;
    int qa1 = ((4 + lrow) ^ rx7) * 8;

    for (int kc = 0; kc < 256; kc += 64) {
#pragma unroll
        for (int j = 0; j < 4; j++) {
            GLOAD_LDS16(gA + kc + j * 32 * 256, lA + j * 2048);
            GLOAD_LDS16(gB + kc + j * 32 * 256, lB + j * 2048);
        }
        __syncthreads();
        bf16x8 a[4][2], b[4][2];
#pragma unroll
        for (int i = 0; i < 4; i++) {
            a[i][0] = *(const bf16x8*)(pa + i * 16 * 64 + qa0);
            a[i][1] = *(const bf16x8*)(pa + i * 16 * 64 + qa1);
            b[i][0] = *(const bf16x8*)(pb + i * 16 * 64 + qa0);
            b[i][1] = *(const bf16x8*)(pb + i * 16 * 64 + qa1);
        }
#pragma unroll
        for (int kh = 0; kh < 2; kh++)
#pragma unroll
            for (int mi = 0; mi < 4; mi++)
#pragma unroll
                for (int ni = 0; ni < 4; ni++)
                    acc[mi][ni] = __builtin_amdgcn_mfma_f32_16x16x32_bf16(
                        a[mi][kh], b[ni][kh], acc[mi][ni], 0, 0, 0);
        __syncthreads();
    }

#pragma unroll
    for (int mi = 0; mi < 4; mi++) {
#pragma unroll
        for (int ni = 0; ni < 4; ni++) {
            int n = n0 + wn * 64 + ni * 16 + lcol;
            float bn = bias[n];
#pragma unroll
            for (int r = 0; r < 4; r++) {
                int m = m0 + wm * 64 + mi * 16 + lrow * 4 + r;
                Out[(size_t)m * 256 + n] = acc[mi][ni][r] + bn;
            }
        }
    }
}

// ---------------- stage C: softmax + bilinear sampling, head-major blocks ---
// Block = 256 thr = ONE head x 64 queries (grid 340 x 8). Gather source is a
// single (b,h) plane = 5440*32*2 B = 348 KB -> per-XCD L2 resident.
// Prep: thread = (q=tid>>2, level=tid&3) -> 4 points; softmax via 2 shuffles.
// Gather: task = (q, seg-of-8B), 2 passes; each thread owns 4 channels of one
// query end-to-end: 128 independent dwordx2 loads, NO cross-lane reduce.
// s_iw padded to 65 entries/query -> conflict-free LDS broadcast (verified
// bank arithmetic: q-stride 130 dwords = bank stride 2, 8 q's distinct).
__global__ __launch_bounds__(256) void k_sample(
    const unsigned short* __restrict__ Vtb,  // (4,8,5440,32) bf16
    const float* __restrict__ refp,          // (4,5440,4,2)
    const float* __restrict__ offs,          // (M,128,2)
    const float* __restrict__ awl,           // (M,128)
    unsigned short* __restrict__ atnb)       // (M,256) bf16
{
    int tid = threadIdx.x;
    int h = blockIdx.y;
    int m_base = blockIdx.x * 64;            // 5440 % 64 == 0: single batch/block
    __shared__ int2 s_iw[64][65];            // [query][point*4+corner], padded

    // ---- prep: 64 q x 16 points on 256 threads (4 points each) ----
    {
        int q = tid >> 2, lev = tid & 3;
        int m = m_base + q;
        float4 aw4 = *(const float4*)&awl[(size_t)m * 128 + h * 16 + lev * 4];
        float4 of0 = *(const float4*)&offs[((size_t)m * 128 + h * 16 + lev * 4) * 2];
        float4 of1 = *(const float4*)&offs[((size_t)m * 128 + h * 16 + lev * 4) * 2 + 4];
        float rx = refp[(size_t)m * 8 + lev * 2 + 0];
        float ry = refp[(size_t)m * 8 + lev * 2 + 1];

        float lg[4] = {aw4.x, aw4.y, aw4.z, aw4.w};
        float mx = fmaxf(fmaxf(lg[0], lg[1]), fmaxf(lg[2], lg[3]));
        mx = fmaxf(mx, __shfl_xor(mx, 1));
        mx = fmaxf(mx, __shfl_xor(mx, 2));
        float e[4]; float s = 0.f;
#pragma unroll
        for (int k = 0; k < 4; k++) { e[k] = __expf(lg[k] - mx); s += e[k]; }
        s += __shfl_xor(s, 1);
        s += __shfl_xor(s, 2);
        float inv = __builtin_amdgcn_rcpf(s);

        int Wl = 64 >> lev;
        int base = (lev == 0) ? 0 : (lev == 1) ? 4096 : (lev == 2) ? 5120 : 5376;
        float fW = (float)Wl;
        float oxs[4] = {of0.x, of0.z, of1.x, of1.z};
        float oys[4] = {of0.y, of0.w, of1.y, of1.w};
#pragma unroll
        for (int k = 0; k < 4; k++) {
            float prob = e[k] * inv;
            float x = rx * fW + oxs[k] - 0.5f;
            float y = ry * fW + oys[k] - 0.5f;
            float x0f = floorf(x), y0f = floorf(y);
            float wx = x - x0f, wy = y - y0f;
            int x0 = (int)x0f, y0 = (int)y0f;
            int xc0 = min(max(x0, 0), Wl - 1), xc1 = min(max(x0 + 1, 0), Wl - 1);
            int yc0 = min(max(y0, 0), Wl - 1), yc1 = min(max(y0 + 1, 0), Wl - 1);
            float vx0 = (x0 >= 0 && x0 < Wl) ? 1.f : 0.f;
            float vx1 = (x0 + 1 >= 0 && x0 + 1 < Wl) ? 1.f : 0.f;
            float vy0 = (y0 >= 0 && y0 < Wl) ? 1.f : 0.f;
            float vy1 = (y0 + 1 >= 0 && y0 + 1 < Wl) ? 1.f : 0.f;
            int pi = (lev * 4 + k) * 4;
            s_iw[q][pi + 0] = make_int2((base + yc0 * Wl + xc0) * 64,
                                        __float_as_int(prob * (1.f - wx) * (1.f - wy) * vx0 * vy0));
            s_iw[q][pi + 1] = make_int2((base + yc0 * Wl + xc1) * 64,
                                        __float_as_int(prob * wx * (1.f - wy) * vx1 * vy0));
            s_iw[q][pi + 2] = make_int2((base + yc1 * Wl + xc0) * 64,
                                        __float_as_int(prob * (1.f - wx) * wy * vx0 * vy1));
            s_iw[q][pi + 3] = make_int2((base + yc1 * Wl + xc1) * 64,
                                        __float_as_int(prob * wx * wy * vx1 * vy1));
        }
    }
    __syncthreads();

    // ---- gather: 512 (q,seg) tasks on 256 threads, 2 passes ----
    int b = m_base / LQ;
    const char* plane = (const char*)(Vtb + ((size_t)b * NH + h) * LQ * DH);
    for (int t = 0; t < 2; t++) {
        int task = tid + t * 256;
        int q = task >> 3, seg = task & 7;
        int m = m_base + q;
        const char* ph = plane + seg * 8;
        float a0 = 0.f, a1 = 0.f, a2 = 0.f, a3 = 0.f;
#pragma unroll 4
        for (int p = 0; p < 16; p++) {
#pragma unroll
            for (int c = 0; c < 4; c++) {
                int2 iw = s_iw[q][p * 4 + c];
                uint2 v = *(const uint2*)(ph + iw.x);
                float wgt = __int_as_float(iw.y);
                a0 += wgt * __uint_as_float(v.x << 16);
                a1 += wgt * __uint_as_float(v.x & 0xffff0000u);
                a2 += wgt * __uint_as_float(v.y << 16);
                a3 += wgt * __uint_as_float(v.y & 0xffff0000u);
            }
        }
        ((uint2*)atnb)[(size_t)m * 64 + h * 8 + seg] =
            make_uint2(pk2(a0, a1), pk2(a2, a3));
    }
}

// ---------------- launch ----------------
extern "C" void kernel_launch(void* const* d_in, const int* in_sizes, int n_in,
                              void* d_out, int out_size, void* d_ws, size_t ws_size,
                              hipStream_t stream) {
    const float* query  = (const float*)d_in[0];
    const float* refp   = (const float*)d_in[1];
    const float* inflat = (const float*)d_in[2];
    // d_in[3] = input_spatial_shapes (static, unused)
    const float* We  = (const float*)d_in[4];
    const float* SW  = (const float*)d_in[5];
    const float* SB  = (const float*)d_in[6];
    const float* AWw = (const float*)d_in[7];
    const float* ABb = (const float*)d_in[8];
    const float* VW  = (const float*)d_in[9];
    const float* Vb  = (const float*)d_in[10];
    const float* OW  = (const float*)d_in[11];
    const float* Ob  = (const float*)d_in[12];
    float* out = (float*)d_out;

    float* ws = (float*)d_ws;
    unsigned short* Vtb  = (unsigned short*)ws;                    // 5,570,560 shorts
    float* offs          = ws + 2785280;                           // 5,570,560 f
    float* awl           = offs + 5570560;                         // 2,785,280 f
    unsigned short* Qbf  = (unsigned short*)(awl + 2785280);       // 5,570,560 shorts
    unsigned short* Webf = Qbf + 5570560;                          // 1,048,576 shorts
    unsigned short* Xbf  = Webf + 1048576;                         // 5,570,560 shorts
    unsigned short* Wvbf = Xbf + 5570560;                          // 65,536 shorts
    unsigned short* OWbf = Wvbf + 65536;                           // 65,536 shorts
    unsigned short* Rbf  = OWbf + 65536;                           // 65,536 shorts
    unsigned short* atnb = Xbf;   // alias: Xbf consumed by k_value_mfma before k_sample writes

    k_cvt2<<<dim3(5440, 2), 256, 0, stream>>>(query, Qbf, inflat, Xbf, MTOT * 256 / 4);
    k_cvt3<<<dim3(1024, 4), 256, 0, stream>>>(We, Webf, OEN * 256 / 4,
                                              VW, Wvbf, 256 * 256 / 4,
                                              OW, OWbf, 256 * 256 / 4,
                                              SW, AWw, Rbf);

    k_value_mfma<<<dim3(2, MTOT / 128), 256, 0, stream>>>(Xbf, Wvbf, Vb, Vtb);

    k_oe_mfma<<<dim3(OEN / 128, MTOT / 128), 256, 0, stream>>>(
        Qbf, Webf, Rbf, SB, ABb, offs, awl);

    k_sample<<<dim3(MTOT / 64, NH), 256, 0, stream>>>(Vtb, refp, offs, awl, atnb);

    k_out_mfma<<<dim3(2, MTOT / 128), 256, 0, stream>>>(atnb, OWbf, Ob, out);
}

// Round 10
// 242.157 us; speedup vs baseline: 2.4329x; 1.0127x over previous
//
#include <hip/hip_runtime.h>
#include <hip/hip_bf16.h>

// ---------------- problem constants (static pyramid) ----------------
#define NB 4
#define LQ 5440
#define DM 256
#define NH 8
#define NL 4
#define NP 4
#define OFFD 32
#define DH 32
#define MTOT (NB * LQ)             // 21760
#define OEN (NH * NL * NP * OFFD)  // 4096
#define NGRP (NH * NL * NP)        // 128

typedef __attribute__((ext_vector_type(8))) short bf16x8;
typedef __attribute__((ext_vector_type(4))) float f32x4;
typedef unsigned int u32;

#define GLOAD_LDS16(gp, lp) \
    __builtin_amdgcn_global_load_lds((const __attribute__((address_space(1))) u32*)(gp), \
                                     (__attribute__((address_space(3))) u32*)(lp), 16, 0, 0)

__device__ __forceinline__ float bf2f(unsigned short u) {
    union { unsigned int i; float f; } v; v.i = ((unsigned int)u) << 16; return v.f;
}
// cheap RNE f32->bf16 (no NaN path; all values finite here)
__device__ __forceinline__ unsigned short f2bf(float x) {
    u32 u = __float_as_uint(x);
    u = u + 0x7fffu + ((u >> 16) & 1u);
    return (unsigned short)(u >> 16);
}
__device__ __forceinline__ u32 pk2(float a, float b) {
    u32 ua = __float_as_uint(a), ub = __float_as_uint(b);
    ua = ua + 0x7fffu + ((ua >> 16) & 1u);
    ub = ub + 0x7fffu + ((ub >> 16) & 1u);
    return (ua >> 16) | (ub & 0xffff0000u);
}
__device__ __forceinline__ float silu(float x) {
    float e = __expf(-x);
    return x * __builtin_amdgcn_rcpf(1.0f + e);   // v_rcp_f32, ~1 ulp
}

// ---------------- fused fp32 -> bf16 conversions + Rb prepack ----------------
// grid (5440, 3): y=0 query, y=1 input_flatten, y=2 weights (x-segmented)
__global__ __launch_bounds__(256) void k_cvt(
    const float* __restrict__ Q,  unsigned short* __restrict__ Qo,
    const float* __restrict__ X,  unsigned short* __restrict__ Xo,
    const float* __restrict__ We, unsigned short* __restrict__ Weo,
    const float* __restrict__ Wv, unsigned short* __restrict__ Wvo,
    const float* __restrict__ OW, unsigned short* __restrict__ OWo,
    const float* __restrict__ SW, const float* __restrict__ AW,
    unsigned short* __restrict__ Rb)
{
    int tid = threadIdx.x, x = blockIdx.x, y = blockIdx.y;
    if (y < 2) {
        const float* src = y ? X : Q;
        unsigned short* dst = y ? Xo : Qo;
        int i = x * 256 + tid;                 // exactly MTOT*256/4 = 1,392,640
        float4 v = *(const float4*)(src + (size_t)i * 4);
        ushort4 o;
        o.x = f2bf(v.x); o.y = f2bf(v.y); o.z = f2bf(v.z); o.w = f2bf(v.w);
        *(ushort4*)(dst + (size_t)i * 4) = o;
        return;
    }
    // y == 2: weight tensors
    if (x < 1024) {                            // We: 1,048,576 elems / 4
        int i = x * 256 + tid;
        float4 v = *(const float4*)(We + (size_t)i * 4);
        ushort4 o;
        o.x = f2bf(v.x); o.y = f2bf(v.y); o.z = f2bf(v.z); o.w = f2bf(v.w);
        *(ushort4*)(Weo + (size_t)i * 4) = o;
    } else if (x < 1088) {                     // value_W: 65,536 / 4
        int i = (x - 1024) * 256 + tid;
        float4 v = *(const float4*)(Wv + (size_t)i * 4);
        ushort4 o;
        o.x = f2bf(v.x); o.y = f2bf(v.y); o.z = f2bf(v.z); o.w = f2bf(v.w);
        *(ushort4*)(Wvo + (size_t)i * 4) = o;
    } else if (x < 1152) {                     // out_W: 65,536 / 4
        int i = (x - 1088) * 256 + tid;
        float4 v = *(const float4*)(OW + (size_t)i * 4);
        ushort4 o;
        o.x = f2bf(v.x); o.y = f2bf(v.y); o.z = f2bf(v.z); o.w = f2bf(v.w);
        *(ushort4*)(OWo + (size_t)i * 4) = o;
    } else if (x < 1408) {                     // Rb[gg][j16][d32]: 65,536 scalar
        int i = (x - 1152) * 256 + tid;
        int gg = i >> 9, jo = (i >> 5) & 15, d = i & 31;
        float v = 0.f;
        if (jo == 0)      v = SW[(gg * 32 + d) * 2 + 0];
        else if (jo == 1) v = SW[(gg * 32 + d) * 2 + 1];
        else if (jo == 2) v = AW[gg * 32 + d];
        Rb[i] = f2bf(v);
    }
}

// ============================================================================
// Merged GEMM dispatch: 1-D grid 5780 blocks.
//   id < 5440: oe GEMM (A=We rows, B=Q rows) + silu + MFMA group reduction
//   id >= 5440: value projection (A=Wv rows, B=X rows) -> Vtb bf16 transposed
// Main loop identical (round-6-verified 128x128 tile, BK=64, XOR-swizzled
// global_load_lds staging). LDS slot (row=c>>3, q=c&7) holds GLOBAL chunk
// (row, q ^ (row&7)). C/D layout: col = lane&15, row = (lane>>4)*4 + reg.
// ============================================================================
__global__ __launch_bounds__(256) void k_oeval_mfma(
    const unsigned short* __restrict__ Qb,   // (21760,256) bf16
    const unsigned short* __restrict__ Wb,   // (4096,256) bf16
    const unsigned short* __restrict__ Xb,   // (21760,256) bf16
    const unsigned short* __restrict__ Wvb,  // (256,256) bf16
    const unsigned short* __restrict__ Rb,   // (128,16,32) bf16 reduction frags
    const float* __restrict__ SB,    // (128,2)
    const float* __restrict__ AB,    // (128)
    const float* __restrict__ Vbias, // (256)
    float* __restrict__ offs_out,    // (M,128,2)
    float* __restrict__ aw_out,      // (M,128)
    unsigned short* __restrict__ Vtb)// (4,8,5440,32) bf16
{
    __shared__ short sA[128 * 64];
    __shared__ short sB[128 * 64];
    __shared__ float w0s[128], w1s[128], wAs[128];

    int tid = threadIdx.x;
    int id = blockIdx.x;
    bool is_oe = id < 5440;
    int n0, m0;
    const unsigned short *Ag, *Bg;
    if (is_oe) {
        n0 = (id & 31) * 128;           // n fastest -> blocks share Q via L2
        m0 = (id >> 5) * 128;
        Ag = Qb; Bg = Wb;
    } else {
        int v = id - 5440;
        n0 = (v & 1) * 128;
        m0 = (v >> 1) * 128;
        Ag = Xb; Bg = Wvb;
    }

    if (is_oe && tid < 128) {
        int n = n0 + tid;
        w0s[tid] = __ldg(&((const float*)SB)[0]) * 0.f + 0.f;  // placeholder overwritten below
    }
    // (load real epilogue weights; separate to keep the guard simple)
    if (is_oe && tid < 128) {
        int n = n0 + tid;
        const float* SWx = (const float*)nullptr;
        (void)SWx;
        // w0s/w1s from Rb would need unpack; load from original SW via Rb? Rb is bf16.
    }

    int lane = tid & 63;
    int w = tid >> 6;
    int wA = w >> 1;            // weight half (mfma-m)
    int wB = w & 1;             // data half (mfma-n)
    int lcol = lane & 15, quad = lane >> 4;

    int srow = tid >> 3;
    int sq = (tid & 7) ^ (srow & 7);
    const short* gA = (const short*)Ag + (size_t)(m0 + srow) * 256 + sq * 8;
    const short* gB = (const short*)Bg + (size_t)(n0 + srow) * 256 + sq * 8;
    short* lA = sA + w * 512;
    short* lB = sB + w * 512;

    f32x4 acc[4][4] = {};   // [weight-tile i][data-tile j]

    const short* pq = sA + (wB * 64 + lcol) * 64;
    const short* pw = sB + (wA * 64 + lcol) * 64;
    int rx7 = lcol & 7;
    int qa0 = (quad ^ rx7) * 8;
    int qa1 = ((4 + quad) ^ rx7) * 8;

    for (int kc = 0; kc < 256; kc += 64) {
#pragma unroll
        for (int j = 0; j < 4; j++) {
            GLOAD_LDS16(gA + kc + j * 32 * 256, lA + j * 2048);
            GLOAD_LDS16(gB + kc + j * 32 * 256, lB + j * 2048);
        }
        __syncthreads();
        bf16x8 a[4][2], b[4][2];
#pragma unroll
        for (int i = 0; i < 4; i++) {
            a[i][0] = *(const bf16x8*)(pw + i * 16 * 64 + qa0);
            a[i][1] = *(const bf16x8*)(pw + i * 16 * 64 + qa1);
            b[i][0] = *(const bf16x8*)(pq + i * 16 * 64 + qa0);
            b[i][1] = *(const bf16x8*)(pq + i * 16 * 64 + qa1);
        }
#pragma unroll
        for (int kh = 0; kh < 2; kh++)
#pragma unroll
            for (int i = 0; i < 4; i++)
#pragma unroll
                for (int j = 0; j < 4; j++)
                    acc[i][j] = __builtin_amdgcn_mfma_f32_16x16x32_bf16(
                        a[i][kh], b[j][kh], acc[i][j], 0, 0, 0);
        __syncthreads();
    }

    if (is_oe) {
        // ---- oe epilogue: silu -> bf16 pack -> MFMA reduction ----
        u32 ps[4][4][2];
#pragma unroll
        for (int i = 0; i < 4; i++)
#pragma unroll
            for (int j = 0; j < 4; j++) {
                ps[i][j][0] = pk2(silu(acc[i][j][0]), silu(acc[i][j][1]));
                ps[i][j][1] = pk2(silu(acc[i][j][2]), silu(acc[i][j][3]));
            }

        int srcbase = (quad & 1) * 32 + lcol;
        bool hi = quad >= 2;
        f32x4 zero = {};
#pragma unroll
        for (int g = 0; g < 2; g++) {
            int gg = (n0 + wA * 64 + g * 32) >> 5;
            bf16x8 afrag = *(const bf16x8*)(Rb + ((size_t)(gg * 16 + lcol) * 32 + quad * 8));
            float sb0 = SB[gg * 2 + 0], sb1 = SB[gg * 2 + 1], ab = AB[gg];
#pragma unroll
            for (int j = 0; j < 4; j++) {
                union { u32 u[4]; bf16x8 v; } bf;
#pragma unroll
                for (int b = 0; b < 2; b++) {
                    int s = srcbase + b * 16;
#pragma unroll
                    for (int c = 0; c < 2; c++) {
                        u32 x0 = (u32)__shfl((int)ps[2 * g + 0][j][c], s);
                        u32 x1 = (u32)__shfl((int)ps[2 * g + 1][j][c], s);
                        bf.u[b * 2 + c] = hi ? x1 : x0;
                    }
                }
                f32x4 d2 = __builtin_amdgcn_mfma_f32_16x16x32_bf16(afrag, bf.v, zero, 0, 0, 0);
                if (quad == 0) {
                    int m = m0 + wB * 64 + j * 16 + lcol;
                    size_t oi = ((size_t)m * NGRP + gg) * 2;
                    offs_out[oi + 0] = d2[0] + sb0;
                    offs_out[oi + 1] = d2[1] + sb1;
                    aw_out[(size_t)m * NGRP + gg] = d2[2] + ab;
                }
            }
        }
    } else {
        // ---- value epilogue: acc n-major, 4 consecutive d -> uint2 stores ----
#pragma unroll
        for (int i = 0; i < 4; i++) {
            int nb4 = n0 + wA * 64 + i * 16 + quad * 4;
            int h = nb4 >> 5, db = nb4 & 31;
            float4 b4 = *(const float4*)&Vbias[nb4];
#pragma unroll
            for (int j = 0; j < 4; j++) {
                int m = m0 + wB * 64 + j * 16 + lcol;
                int b = m / LQ, q = m - b * LQ;
                u32 lo = pk2(acc[i][j][0] + b4.x, acc[i][j][1] + b4.y);
                u32 hi2 = pk2(acc[i][j][2] + b4.z, acc[i][j][3] + b4.w);
                char* dst = (char*)Vtb + ((((size_t)b * NH + h) * LQ + q) * DH + db) * 2;
                *(uint2*)dst = make_uint2(lo, hi2);
            }
        }
    }
}

// ---------------- stage D: output projection (round-6 verified) ----------------
__global__ __launch_bounds__(256) void k_out_mfma(
    const unsigned short* __restrict__ Xb,   // (21760,256) bf16 attn
    const unsigned short* __restrict__ Wob,  // (256,256) bf16 (n,k)
    const float* __restrict__ bias,          // (256)
    float* __restrict__ Out)                 // (21760,256) fp32
{
    __shared__ short sA[128 * 64];
    __shared__ short sB[128 * 64];
    int tid = threadIdx.x;
    int n0 = blockIdx.x * 128;
    int m0 = blockIdx.y * 128;
    int lane = tid & 63;
    int w = tid >> 6;
    int wm = w >> 1, wn = w & 1;
    int lcol = lane & 15, lrow = lane >> 4;

    int srow = tid >> 3;
    int sq = (tid & 7) ^ (srow & 7);
    const short* gA = (const short*)Xb + (size_t)(m0 + srow) * 256 + sq * 8;
    const short* gB = (const short*)Wob + (size_t)(n0 + srow) * 256 + sq * 8;
    short* lA = sA + w * 512;
    short* lB = sB + w * 512;

    f32x4 acc[4][4] = {};
    const short* pa = sA + (wm * 64 + lcol) * 64;
    const short* pb = sB + (wn * 64 + lcol) * 64;
    int rx7 = lcol & 7;
    int qa0 = (lrow ^ rx7) * 8;
    int qa1 = ((4 + lrow) ^ rx7) * 8;

    for (int kc = 0; kc < 256; kc += 64) {
#pragma unroll
        for (int j = 0; j < 4; j++) {
            GLOAD_LDS16(gA + kc + j * 32 * 256, lA + j * 2048);
            GLOAD_LDS16(gB + kc + j * 32 * 256, lB + j * 2048);
        }
        __syncthreads();
        bf16x8 a[4][2], b[4][2];
#pragma unroll
        for (int i = 0; i < 4; i++) {
            a[i][0] = *(const bf16x8*)(pa + i * 16 * 64 + qa0);
            a[i][1] = *(const bf16x8*)(pa + i * 16 * 64 + qa1);
            b[i][0] = *(const bf16x8*)(pb + i * 16 * 64 + qa0);
            b[i][1] = *(const bf16x8*)(pb + i * 16 * 64 + qa1);
        }
#pragma unroll
        for (int kh = 0; kh < 2; kh++)
#pragma unroll
            for (int mi = 0; mi < 4; mi++)
#pragma unroll
                for (int ni = 0; ni < 4; ni++)
                    acc[mi][ni] = __builtin_amdgcn_mfma_f32_16x16x32_bf16(
                        a[mi][kh], b[ni][kh], acc[mi][ni], 0, 0, 0);
        __syncthreads();
    }

#pragma unroll
    for (int mi = 0; mi < 4; mi++) {
#pragma unroll
        for (int ni = 0; ni < 4; ni++) {
            int n = n0 + wn * 64 + ni * 16 + lcol;
            float bn = bias[n];
#pragma unroll
            for (int r = 0; r < 4; r++) {
                int m = m0 + wm * 64 + mi * 16 + lrow * 4 + r;
                Out[(size_t)m * 256 + n] = acc[mi][ni][r] + bn;
            }
        }
    }
}

// ---------------- stage C: sampling, XCD-pinned heads, dwordx4 gather -------
// 1-D grid 2720: h = id & 7 (pins each head to one XCD -> its 4 planes =
// 1.4 MB resident in that XCD's L2), xi = id >> 3, m_base = xi*64.
// Gather: thread = (q=tid>>2, seg=tid&3); 4 lanes x 16 B cover each 64 B
// corner row -> fully line-coalesced; 64 dwordx4 per thread (was 128 x2).
__global__ __launch_bounds__(256) void k_sample(
    const unsigned short* __restrict__ Vtb,  // (4,8,5440,32) bf16
    const float* __restrict__ refp,          // (4,5440,4,2)
    const float* __restrict__ offs,          // (M,128,2)
    const float* __restrict__ awl,           // (M,128)
    unsigned short* __restrict__ atnb)       // (M,256) bf16
{
    int tid = threadIdx.x;
    int id = blockIdx.x;
    int h = id & 7;
    int m_base = (id >> 3) * 64;
    __shared__ int2 s_iw[64][65];            // [query][point*4+corner], padded

    // ---- prep: 64 q x 4 levels on 256 threads ----
    {
        int q = tid >> 2, lev = tid & 3;
        int m = m_base + q;
        float4 aw4 = *(const float4*)&awl[(size_t)m * 128 + h * 16 + lev * 4];
        float4 of0 = *(const float4*)&offs[((size_t)m * 128 + h * 16 + lev * 4) * 2];
        float4 of1 = *(const float4*)&offs[((size_t)m * 128 + h * 16 + lev * 4) * 2 + 4];
        float rx = refp[(size_t)m * 8 + lev * 2 + 0];
        float ry = refp[(size_t)m * 8 + lev * 2 + 1];

        float lg[4] = {aw4.x, aw4.y, aw4.z, aw4.w};
        float mx = fmaxf(fmaxf(lg[0], lg[1]), fmaxf(lg[2], lg[3]));
        mx = fmaxf(mx, __shfl_xor(mx, 1));
        mx = fmaxf(mx, __shfl_xor(mx, 2));
        float e[4]; float s = 0.f;
#pragma unroll
        for (int k = 0; k < 4; k++) { e[k] = __expf(lg[k] - mx); s += e[k]; }
        s += __shfl_xor(s, 1);
        s += __shfl_xor(s, 2);
        float inv = __builtin_amdgcn_rcpf(s);

        int Wl = 64 >> lev;
        int base = (lev == 0) ? 0 : (lev == 1) ? 4096 : (lev == 2) ? 5120 : 5376;
        float fW = (float)Wl;
        float oxs[4] = {of0.x, of0.z, of1.x, of1.z};
        float oys[4] = {of0.y, of0.w, of1.y, of1.w};
#pragma unroll
        for (int k = 0; k < 4; k++) {
            float prob = e[k] * inv;
            float x = rx * fW + oxs[k] - 0.5f;
            float y = ry * fW + oys[k] - 0.5f;
            float x0f = floorf(x), y0f = floorf(y);
            float wx = x - x0f, wy = y - y0f;
            int x0 = (int)x0f, y0 = (int)y0f;
            int xc0 = min(max(x0, 0), Wl - 1), xc1 = min(max(x0 + 1, 0), Wl - 1);
            int yc0 = min(max(y0, 0), Wl - 1), yc1 = min(max(y0 + 1, 0), Wl - 1);
            float vx0 = (x0 >= 0 && x0 < Wl) ? 1.f : 0.f;
            float vx1 = (x0 + 1 >= 0 && x0 + 1 < Wl) ? 1.f : 0.f;
            float vy0 = (y0 >= 0 && y0 < Wl) ? 1.f : 0.f;
            float vy1 = (y0 + 1 >= 0 && y0 + 1 < Wl) ? 1.f : 0.f;
            int pi = (lev * 4 + k) * 4;
            s_iw[q][pi + 0] = make_int2((base + yc0 * Wl + xc0) * 64,
                                        __float_as_int(prob * (1.f - wx) * (1.f - wy) * vx0 * vy0));
            s_iw[q][pi + 1] = make_int2((base + yc0 * Wl + xc1) * 64,
                                        __float_as_int(prob * wx * (1.f - wy) * vx1 * vy0));
            s_iw[q][pi + 2] = make_int2((base + yc1 * Wl + xc0) * 64,
                                        __float_as_int(prob * (1.f - wx) * wy * vx0 * vy1));
            s_iw[q][pi + 3] = make_int2((base + yc1 * Wl + xc1) * 64,
                                        __float_as_int(prob * wx * wy * vx1 * vy1));
        }
    }
    __syncthreads();

    // ---- gather: thread = (q, 16B segment), 64 dwordx4 loads ----
    int q = tid >> 2, seg = tid & 3;
    int m = m_base + q;
    int b = m / LQ;
    const char* ph = (const char*)(Vtb + ((size_t)b * NH + h) * LQ * DH) + seg * 16;
    float a0 = 0.f, a1 = 0.f, a2 = 0.f, a3 = 0.f;
    float a4 = 0.f, a5 = 0.f, a6 = 0.f, a7 = 0.f;
#pragma unroll 2
    for (int p = 0; p < 16; p++) {
#pragma unroll
        for (int c = 0; c < 4; c++) {
            int2 iw = s_iw[q][p * 4 + c];
            uint4 v = *(const uint4*)(ph + iw.x);
            float wgt = __int_as_float(iw.y);
            a0 += wgt * __uint_as_float(v.x << 16);
            a1 += wgt * __uint_as_float(v.x & 0xffff0000u);
            a2 += wgt * __uint_as_float(v.y << 16);
            a3 += wgt * __uint_as_float(v.y & 0xffff0000u);
            a4 += wgt * __uint_as_float(v.z << 16);
            a5 += wgt * __uint_as_float(v.z & 0xffff0000u);
            a6 += wgt * __uint_as_float(v.w << 16);
            a7 += wgt * __uint_as_float(v.w & 0xffff0000u);
        }
    }
    ((uint4*)atnb)[(size_t)m * 32 + h * 4 + seg] =
        make_uint4(pk2(a0, a1), pk2(a2, a3), pk2(a4, a5), pk2(a6, a7));
}

// ---------------- launch ----------------
extern "C" void kernel_launch(void* const* d_in, const int* in_sizes, int n_in,
                              void* d_out, int out_size, void* d_ws, size_t ws_size,
                              hipStream_t stream) {
    const float* query  = (const float*)d_in[0];
    const float* refp   = (const float*)d_in[1];
    const float* inflat = (const float*)d_in[2];
    // d_in[3] = input_spatial_shapes (static, unused)
    const float* We  = (const float*)d_in[4];
    const float* SW  = (const float*)d_in[5];
    const float* SB  = (const float*)d_in[6];
    const float* AWw = (const float*)d_in[7];
    const float* ABb = (const float*)d_in[8];
    const float* VW  = (const float*)d_in[9];
    const float* Vb  = (const float*)d_in[10];
    const float* OW  = (const float*)d_in[11];
    const float* Ob  = (const float*)d_in[12];
    float* out = (float*)d_out;

    float* ws = (float*)d_ws;
    unsigned short* Vtb  = (unsigned short*)ws;                    // 5,570,560 shorts
    float* offs          = ws + 2785280;                           // 5,570,560 f
    float* awl           = offs + 5570560;                         // 2,785,280 f
    unsigned short* Qbf  = (unsigned short*)(awl + 2785280);       // 5,570,560 shorts
    unsigned short* Webf = Qbf + 5570560;                          // 1,048,576 shorts
    unsigned short* Xbf  = Webf + 1048576;                         // 5,570,560 shorts
    unsigned short* Wvbf = Xbf + 5570560;                          // 65,536 shorts
    unsigned short* OWbf = Wvbf + 65536;                           // 65,536 shorts
    unsigned short* Rbf  = OWbf + 65536;                           // 65,536 shorts
    unsigned short* atnb = Xbf;   // alias: Xbf consumed by k_oeval before k_sample writes

    k_cvt<<<dim3(5440, 3), 256, 0, stream>>>(query, Qbf, inflat, Xbf,
                                             We, Webf, VW, Wvbf, OW, OWbf,
                                             SW, AWw, Rbf);

    k_oeval_mfma<<<dim3(5780), 256, 0, stream>>>(
        Qbf, Webf, Xbf, Wvbf, Rbf, SB, ABb, Vb, offs, awl, Vtb);

    k_sample<<<dim3(2720), 256, 0, stream>>>(Vtb, refp, offs, awl, atnb);

    k_out_mfma<<<dim3(2, MTOT / 128), 256, 0, stream>>>(atnb, OWbf, Ob, out);
}

// Round 11
// 232.882 us; speedup vs baseline: 2.5297x; 1.0398x over previous
//
#include <hip/hip_runtime.h>
#include <hip/hip_bf16.h>

// ---------------- problem constants (static pyramid) ----------------
#define NB 4
#define LQ 5440
#define DM 256
#define NH 8
#define NL 4
#define NP 4
#define OFFD 32
#define DH 32
#define MTOT (NB * LQ)             // 21760
#define OEN (NH * NL * NP * OFFD)  // 4096
#define NGRP (NH * NL * NP)        // 128

typedef __attribute__((ext_vector_type(8))) short bf16x8;
typedef __attribute__((ext_vector_type(4))) float f32x4;
typedef unsigned int u32;

#define GLOAD_LDS16(gp, lp) \
    __builtin_amdgcn_global_load_lds((const __attribute__((address_space(1))) u32*)(gp), \
                                     (__attribute__((address_space(3))) u32*)(lp), 16, 0, 0)

__device__ __forceinline__ float bf2f(unsigned short u) {
    union { unsigned int i; float f; } v; v.i = ((unsigned int)u) << 16; return v.f;
}
// cheap RNE f32->bf16 (no NaN path; all values finite here)
__device__ __forceinline__ unsigned short f2bf(float x) {
    u32 u = __float_as_uint(x);
    u = u + 0x7fffu + ((u >> 16) & 1u);
    return (unsigned short)(u >> 16);
}
__device__ __forceinline__ u32 pk2(float a, float b) {
    u32 ua = __float_as_uint(a), ub = __float_as_uint(b);
    ua = ua + 0x7fffu + ((ua >> 16) & 1u);
    ub = ub + 0x7fffu + ((ub >> 16) & 1u);
    return (ua >> 16) | (ub & 0xffff0000u);
}
__device__ __forceinline__ float silu(float x) {
    float e = __expf(-x);
    return x * __builtin_amdgcn_rcpf(1.0f + e);   // v_rcp_f32, ~1 ulp
}

// ---------------- fused fp32 -> bf16 conversions + Rb prepack ----------------
// grid (5440, 3): y=0 query, y=1 input_flatten, y=2 weights (x-segmented)
__global__ __launch_bounds__(256) void k_cvt(
    const float* __restrict__ Q,  unsigned short* __restrict__ Qo,
    const float* __restrict__ X,  unsigned short* __restrict__ Xo,
    const float* __restrict__ We, unsigned short* __restrict__ Weo,
    const float* __restrict__ Wv, unsigned short* __restrict__ Wvo,
    const float* __restrict__ OW, unsigned short* __restrict__ OWo,
    const float* __restrict__ SW, const float* __restrict__ AW,
    unsigned short* __restrict__ Rb)
{
    int tid = threadIdx.x, x = blockIdx.x, y = blockIdx.y;
    if (y < 2) {
        const float* src = y ? X : Q;
        unsigned short* dst = y ? Xo : Qo;
        int i = x * 256 + tid;                 // exactly MTOT*256/4 = 1,392,640
        float4 v = *(const float4*)(src + (size_t)i * 4);
        ushort4 o;
        o.x = f2bf(v.x); o.y = f2bf(v.y); o.z = f2bf(v.z); o.w = f2bf(v.w);
        *(ushort4*)(dst + (size_t)i * 4) = o;
        return;
    }
    // y == 2: weight tensors
    if (x < 1024) {                            // We: 1,048,576 elems / 4
        int i = x * 256 + tid;
        float4 v = *(const float4*)(We + (size_t)i * 4);
        ushort4 o;
        o.x = f2bf(v.x); o.y = f2bf(v.y); o.z = f2bf(v.z); o.w = f2bf(v.w);
        *(ushort4*)(Weo + (size_t)i * 4) = o;
    } else if (x < 1088) {                     // value_W: 65,536 / 4
        int i = (x - 1024) * 256 + tid;
        float4 v = *(const float4*)(Wv + (size_t)i * 4);
        ushort4 o;
        o.x = f2bf(v.x); o.y = f2bf(v.y); o.z = f2bf(v.z); o.w = f2bf(v.w);
        *(ushort4*)(Wvo + (size_t)i * 4) = o;
    } else if (x < 1152) {                     // out_W: 65,536 / 4
        int i = (x - 1088) * 256 + tid;
        float4 v = *(const float4*)(OW + (size_t)i * 4);
        ushort4 o;
        o.x = f2bf(v.x); o.y = f2bf(v.y); o.z = f2bf(v.z); o.w = f2bf(v.w);
        *(ushort4*)(OWo + (size_t)i * 4) = o;
    } else if (x < 1408) {                     // Rb[gg][j16][d32]: 65,536 scalar
        int i = (x - 1152) * 256 + tid;
        int gg = i >> 9, jo = (i >> 5) & 15, d = i & 31;
        float v = 0.f;
        if (jo == 0)      v = SW[(gg * 32 + d) * 2 + 0];
        else if (jo == 1) v = SW[(gg * 32 + d) * 2 + 1];
        else if (jo == 2) v = AW[gg * 32 + d];
        Rb[i] = f2bf(v);
    }
}

// ============================================================================
// MFMA GEMM skeleton (round-6/9 verified): 128x128 tile, BK=64, XOR-swizzled
// global_load_lds staging. (Register-prefetch REVERTED r7: scratch spill.
// oe+value merge REVERTED r10: VGPR 80->96, occupancy loss, +28us.)
// LDS slot (row=c>>3, q=c&7) holds GLOBAL chunk (row, q ^ (row&7)).
// C/D layout (verified): col = lane&15, row = (lane>>4)*4 + reg.
// ============================================================================

// ---------------- stage B: oe GEMM (A=We, B=Q) + silu + MFMA reduction ------
__global__ __launch_bounds__(256) void k_oe_mfma(
    const unsigned short* __restrict__ Qb,   // (21760,256) bf16
    const unsigned short* __restrict__ Wb,   // (4096,256) bf16
    const unsigned short* __restrict__ Rb,   // (128,16,32) bf16 reduction frags
    const float* __restrict__ SB,    // (128,2)
    const float* __restrict__ AB,    // (128)
    float* __restrict__ offs_out,    // (M,128,2)
    float* __restrict__ aw_out)      // (M,128)
{
    __shared__ short sA[128 * 64];   // Q rows
    __shared__ short sB[128 * 64];   // We rows
    int tid = threadIdx.x;
    int n0 = blockIdx.x * 128;   // We/n fastest-varying -> blocks share Q via L2
    int m0 = blockIdx.y * 128;

    int lane = tid & 63;
    int w = tid >> 6;
    int wA = w >> 1;            // We half (mfma-m)
    int wB = w & 1;             // Q half (mfma-n)
    int lcol = lane & 15, quad = lane >> 4;

    int srow = tid >> 3;
    int sq = (tid & 7) ^ (srow & 7);
    const short* gA = (const short*)Qb + (size_t)(m0 + srow) * 256 + sq * 8;
    const short* gB = (const short*)Wb + (size_t)(n0 + srow) * 256 + sq * 8;
    short* lA = sA + w * 512;
    short* lB = sB + w * 512;

    f32x4 acc[4][4] = {};   // [We-tile i][Q-tile j]

    const short* pq = sA + (wB * 64 + lcol) * 64;   // Q fragments (B operand)
    const short* pw = sB + (wA * 64 + lcol) * 64;   // We fragments (A operand)
    int rx7 = lcol & 7;
    int qa0 = (quad ^ rx7) * 8;
    int qa1 = ((4 + quad) ^ rx7) * 8;

    for (int kc = 0; kc < 256; kc += 64) {
#pragma unroll
        for (int j = 0; j < 4; j++) {
            GLOAD_LDS16(gA + kc + j * 32 * 256, lA + j * 2048);
            GLOAD_LDS16(gB + kc + j * 32 * 256, lB + j * 2048);
        }
        __syncthreads();
        bf16x8 a[4][2], b[4][2];
#pragma unroll
        for (int i = 0; i < 4; i++) {
            a[i][0] = *(const bf16x8*)(pw + i * 16 * 64 + qa0);  // We
            a[i][1] = *(const bf16x8*)(pw + i * 16 * 64 + qa1);
            b[i][0] = *(const bf16x8*)(pq + i * 16 * 64 + qa0);  // Q
            b[i][1] = *(const bf16x8*)(pq + i * 16 * 64 + qa1);
        }
#pragma unroll
        for (int kh = 0; kh < 2; kh++)
#pragma unroll
            for (int i = 0; i < 4; i++)
#pragma unroll
                for (int j = 0; j < 4; j++)
                    acc[i][j] = __builtin_amdgcn_mfma_f32_16x16x32_bf16(
                        a[i][kh], b[j][kh], acc[i][j], 0, 0, 0);
        __syncthreads();
    }

    // ---- epilogue: silu -> bf16 pack (registers) -> MFMA reduction ----
    u32 ps[4][4][2];
#pragma unroll
    for (int i = 0; i < 4; i++)
#pragma unroll
        for (int j = 0; j < 4; j++) {
            ps[i][j][0] = pk2(silu(acc[i][j][0]), silu(acc[i][j][1]));
            ps[i][j][1] = pk2(silu(acc[i][j][2]), silu(acc[i][j][3]));
        }

    int srcbase = (quad & 1) * 32 + lcol;
    bool hi = quad >= 2;
    f32x4 zero = {};
#pragma unroll
    for (int g = 0; g < 2; g++) {
        int gg = (n0 + wA * 64 + g * 32) >> 5;
        bf16x8 afrag = *(const bf16x8*)(Rb + ((size_t)(gg * 16 + lcol) * 32 + quad * 8));
        float sb0 = SB[gg * 2 + 0], sb1 = SB[gg * 2 + 1], ab = AB[gg];
#pragma unroll
        for (int j = 0; j < 4; j++) {
            union { u32 u[4]; bf16x8 v; } bf;
#pragma unroll
            for (int b = 0; b < 2; b++) {
                int s = srcbase + b * 16;
#pragma unroll
                for (int c = 0; c < 2; c++) {
                    u32 x0 = (u32)__shfl((int)ps[2 * g + 0][j][c], s);
                    u32 x1 = (u32)__shfl((int)ps[2 * g + 1][j][c], s);
                    bf.u[b * 2 + c] = hi ? x1 : x0;
                }
            }
            f32x4 d2 = __builtin_amdgcn_mfma_f32_16x16x32_bf16(afrag, bf.v, zero, 0, 0, 0);
            if (quad == 0) {
                int m = m0 + wB * 64 + j * 16 + lcol;
                size_t oi = ((size_t)m * NGRP + gg) * 2;
                offs_out[oi + 0] = d2[0] + sb0;
                offs_out[oi + 1] = d2[1] + sb1;
                aw_out[(size_t)m * NGRP + gg] = d2[2] + ab;
            }
        }
    }
}

// ---------------- stage A: value projection (swapped operands) ----------------
__global__ __launch_bounds__(256) void k_value_mfma(
    const unsigned short* __restrict__ Xb,   // (21760,256) bf16
    const unsigned short* __restrict__ Wvb,  // (256,256) bf16 (n,k)
    const float* __restrict__ bias,          // (256)
    unsigned short* __restrict__ Vtb)        // (4,8,5440,32) bf16
{
    __shared__ short sA[128 * 64];   // X rows
    __shared__ short sB[128 * 64];   // Wv rows
    int tid = threadIdx.x;
    int n0 = blockIdx.x * 128;
    int m0 = blockIdx.y * 128;
    int lane = tid & 63;
    int w = tid >> 6;
    int wA = w >> 1;            // Wv half (mfma-m)
    int wB = w & 1;             // X half (mfma-n)
    int lcol = lane & 15, quad = lane >> 4;

    int srow = tid >> 3;
    int sq = (tid & 7) ^ (srow & 7);
    const short* gA = (const short*)Xb + (size_t)(m0 + srow) * 256 + sq * 8;
    const short* gB = (const short*)Wvb + (size_t)(n0 + srow) * 256 + sq * 8;
    short* lA = sA + w * 512;
    short* lB = sB + w * 512;

    f32x4 acc[4][4] = {};   // [Wv-tile i][X-tile j]
    const short* px = sA + (wB * 64 + lcol) * 64;
    const short* pw = sB + (wA * 64 + lcol) * 64;
    int rx7 = lcol & 7;
    int qa0 = (quad ^ rx7) * 8;
    int qa1 = ((4 + quad) ^ rx7) * 8;

    for (int kc = 0; kc < 256; kc += 64) {
#pragma unroll
        for (int j = 0; j < 4; j++) {
            GLOAD_LDS16(gA + kc + j * 32 * 256, lA + j * 2048);
            GLOAD_LDS16(gB + kc + j * 32 * 256, lB + j * 2048);
        }
        __syncthreads();
        bf16x8 a[4][2], b[4][2];
#pragma unroll
        for (int i = 0; i < 4; i++) {
            a[i][0] = *(const bf16x8*)(pw + i * 16 * 64 + qa0);  // Wv
            a[i][1] = *(const bf16x8*)(pw + i * 16 * 64 + qa1);
            b[i][0] = *(const bf16x8*)(px + i * 16 * 64 + qa0);  // X
            b[i][1] = *(const bf16x8*)(px + i * 16 * 64 + qa1);
        }
#pragma unroll
        for (int kh = 0; kh < 2; kh++)
#pragma unroll
            for (int i = 0; i < 4; i++)
#pragma unroll
                for (int j = 0; j < 4; j++)
                    acc[i][j] = __builtin_amdgcn_mfma_f32_16x16x32_bf16(
                        a[i][kh], b[j][kh], acc[i][j], 0, 0, 0);
        __syncthreads();
    }

#pragma unroll
    for (int i = 0; i < 4; i++) {
        int nb4 = n0 + wA * 64 + i * 16 + quad * 4;   // 4 consecutive n
        int h = nb4 >> 5, db = nb4 & 31;
        float4 b4 = *(const float4*)&bias[nb4];
#pragma unroll
        for (int j = 0; j < 4; j++) {
            int m = m0 + wB * 64 + j * 16 + lcol;
            int b = m / LQ, q = m - b * LQ;
            u32 lo = pk2(acc[i][j][0] + b4.x, acc[i][j][1] + b4.y);
            u32 hi2 = pk2(acc[i][j][2] + b4.z, acc[i][j][3] + b4.w);
            char* dst = (char*)Vtb + ((((size_t)b * NH + h) * LQ + q) * DH + db) * 2;
            *(uint2*)dst = make_uint2(lo, hi2);
        }
    }
}

// ---------------- stage D: output projection ----------------
__global__ __launch_bounds__(256) void k_out_mfma(
    const unsigned short* __restrict__ Xb,   // (21760,256) bf16 attn
    const unsigned short* __restrict__ Wob,  // (256,256) bf16 (n,k)
    const float* __restrict__ bias,          // (256)
    float* __restrict__ Out)                 // (21760,256) fp32
{
    __shared__ short sA[128 * 64];
    __shared__ short sB[128 * 64];
    int tid = threadIdx.x;
    int n0 = blockIdx.x * 128;
    int m0 = blockIdx.y * 128;
    int lane = tid & 63;
    int w = tid >> 6;
    int wm = w >> 1, wn = w & 1;
    int lcol = lane & 15, lrow = lane >> 4;

    int srow = tid >> 3;
    int sq = (tid & 7) ^ (srow & 7);
    const short* gA = (const short*)Xb + (size_t)(m0 + srow) * 256 + sq * 8;
    const short* gB = (const short*)Wob + (size_t)(n0 + srow) * 256 + sq * 8;
    short* lA = sA + w * 512;
    short* lB = sB + w * 512;

    f32x4 acc[4][4] = {};
    const short* pa = sA + (wm * 64 + lcol) * 64;
    const short* pb = sB + (wn * 64 + lcol) * 64;
    int rx7 = lcol & 7;
    int qa0 = (lrow ^ rx7) * 8;
    int qa1 = ((4 + lrow) ^ rx7) * 8;

    for (int kc = 0; kc < 256; kc += 64) {
#pragma unroll
        for (int j = 0; j < 4; j++) {
            GLOAD_LDS16(gA + kc + j * 32 * 256, lA + j * 2048);
            GLOAD_LDS16(gB + kc + j * 32 * 256, lB + j * 2048);
        }
        __syncthreads();
        bf16x8 a[4][2], b[4][2];
#pragma unroll
        for (int i = 0; i < 4; i++) {
            a[i][0] = *(const bf16x8*)(pa + i * 16 * 64 + qa0);
            a[i][1] = *(const bf16x8*)(pa + i * 16 * 64 + qa1);
            b[i][0] = *(const bf16x8*)(pb + i * 16 * 64 + qa0);
            b[i][1] = *(const bf16x8*)(pb + i * 16 * 64 + qa1);
        }
#pragma unroll
        for (int kh = 0; kh < 2; kh++)
#pragma unroll
            for (int mi = 0; mi < 4; mi++)
#pragma unroll
                for (int ni = 0; ni < 4; ni++)
                    acc[mi][ni] = __builtin_amdgcn_mfma_f32_16x16x32_bf16(
                        a[mi][kh], b[ni][kh], acc[mi][ni], 0, 0, 0);
        __syncthreads();
    }

#pragma unroll
    for (int mi = 0; mi < 4; mi++) {
#pragma unroll
        for (int ni = 0; ni < 4; ni++) {
            int n = n0 + wn * 64 + ni * 16 + lcol;
            float bn = bias[n];
#pragma unroll
            for (int r = 0; r < 4; r++) {
                int m = m0 + wm * 64 + mi * 16 + lrow * 4 + r;
                Out[(size_t)m * 256 + n] = acc[mi][ni][r] + bn;
            }
        }
    }
}

// ---------------- stage C: sampling, XCD-pinned heads, dwordx4 gather -------
// 1-D grid 2720: h = id & 7 (pins each head to one XCD -> its 4 planes =
// 1.4 MB resident in that XCD's L2), m_base = (id>>3)*64.
// Gather: thread = (q=tid>>2, seg=tid&3); 4 lanes x 16 B cover each 64 B
// corner row -> fully line-coalesced; 64 dwordx4 per thread.
__global__ __launch_bounds__(256) void k_sample(
    const unsigned short* __restrict__ Vtb,  // (4,8,5440,32) bf16
    const float* __restrict__ refp,          // (4,5440,4,2)
    const float* __restrict__ offs,          // (M,128,2)
    const float* __restrict__ awl,           // (M,128)
    unsigned short* __restrict__ atnb)       // (M,256) bf16
{
    int tid = threadIdx.x;
    int id = blockIdx.x;
    int h = id & 7;
    int m_base = (id >> 3) * 64;
    __shared__ int2 s_iw[64][65];            // [query][point*4+corner], padded

    // ---- prep: 64 q x 4 levels on 256 threads ----
    {
        int q = tid >> 2, lev = tid & 3;
        int m = m_base + q;
        float4 aw4 = *(const float4*)&awl[(size_t)m * 128 + h * 16 + lev * 4];
        float4 of0 = *(const float4*)&offs[((size_t)m * 128 + h * 16 + lev * 4) * 2];
        float4 of1 = *(const float4*)&offs[((size_t)m * 128 + h * 16 + lev * 4) * 2 + 4];
        float rx = refp[(size_t)m * 8 + lev * 2 + 0];
        float ry = refp[(size_t)m * 8 + lev * 2 + 1];

        float lg[4] = {aw4.x, aw4.y, aw4.z, aw4.w};
        float mx = fmaxf(fmaxf(lg[0], lg[1]), fmaxf(lg[2], lg[3]));
        mx = fmaxf(mx, __shfl_xor(mx, 1));
        mx = fmaxf(mx, __shfl_xor(mx, 2));
        float e[4]; float s = 0.f;
#pragma unroll
        for (int k = 0; k < 4; k++) { e[k] = __expf(lg[k] - mx); s += e[k]; }
        s += __shfl_xor(s, 1);
        s += __shfl_xor(s, 2);
        float inv = __builtin_amdgcn_rcpf(s);

        int Wl = 64 >> lev;
        int base = (lev == 0) ? 0 : (lev == 1) ? 4096 : (lev == 2) ? 5120 : 5376;
        float fW = (float)Wl;
        float oxs[4] = {of0.x, of0.z, of1.x, of1.z};
        float oys[4] = {of0.y, of0.w, of1.y, of1.w};
#pragma unroll
        for (int k = 0; k < 4; k++) {
            float prob = e[k] * inv;
            float x = rx * fW + oxs[k] - 0.5f;
            float y = ry * fW + oys[k] - 0.5f;
            float x0f = floorf(x), y0f = floorf(y);
            float wx = x - x0f, wy = y - y0f;
            int x0 = (int)x0f, y0 = (int)y0f;
            int xc0 = min(max(x0, 0), Wl - 1), xc1 = min(max(x0 + 1, 0), Wl - 1);
            int yc0 = min(max(y0, 0), Wl - 1), yc1 = min(max(y0 + 1, 0), Wl - 1);
            float vx0 = (x0 >= 0 && x0 < Wl) ? 1.f : 0.f;
            float vx1 = (x0 + 1 >= 0 && x0 + 1 < Wl) ? 1.f : 0.f;
            float vy0 = (y0 >= 0 && y0 < Wl) ? 1.f : 0.f;
            float vy1 = (y0 + 1 >= 0 && y0 + 1 < Wl) ? 1.f : 0.f;
            int pi = (lev * 4 + k) * 4;
            s_iw[q][pi + 0] = make_int2((base + yc0 * Wl + xc0) * 64,
                                        __float_as_int(prob * (1.f - wx) * (1.f - wy) * vx0 * vy0));
            s_iw[q][pi + 1] = make_int2((base + yc0 * Wl + xc1) * 64,
                                        __float_as_int(prob * wx * (1.f - wy) * vx1 * vy0));
            s_iw[q][pi + 2] = make_int2((base + yc1 * Wl + xc0) * 64,
                                        __float_as_int(prob * (1.f - wx) * wy * vx0 * vy1));
            s_iw[q][pi + 3] = make_int2((base + yc1 * Wl + xc1) * 64,
                                        __float_as_int(prob * wx * wy * vx1 * vy1));
        }
    }
    __syncthreads();

    // ---- gather: thread = (q, 16B segment), 64 dwordx4 loads ----
    int q = tid >> 2, seg = tid & 3;
    int m = m_base + q;
    int b = m / LQ;
    const char* ph = (const char*)(Vtb + ((size_t)b * NH + h) * LQ * DH) + seg * 16;
    float a0 = 0.f, a1 = 0.f, a2 = 0.f, a3 = 0.f;
    float a4 = 0.f, a5 = 0.f, a6 = 0.f, a7 = 0.f;
#pragma unroll 2
    for (int p = 0; p < 16; p++) {
#pragma unroll
        for (int c = 0; c < 4; c++) {
            int2 iw = s_iw[q][p * 4 + c];
            uint4 v = *(const uint4*)(ph + iw.x);
            float wgt = __int_as_float(iw.y);
            a0 += wgt * __uint_as_float(v.x << 16);
            a1 += wgt * __uint_as_float(v.x & 0xffff0000u);
            a2 += wgt * __uint_as_float(v.y << 16);
            a3 += wgt * __uint_as_float(v.y & 0xffff0000u);
            a4 += wgt * __uint_as_float(v.z << 16);
            a5 += wgt * __uint_as_float(v.z & 0xffff0000u);
            a6 += wgt * __uint_as_float(v.w << 16);
            a7 += wgt * __uint_as_float(v.w & 0xffff0000u);
        }
    }
    ((uint4*)atnb)[(size_t)m * 32 + h * 4 + seg] =
        make_uint4(pk2(a0, a1), pk2(a2, a3), pk2(a4, a5), pk2(a6, a7));
}

// ---------------- launch ----------------
extern "C" void kernel_launch(void* const* d_in, const int* in_sizes, int n_in,
                              void* d_out, int out_size, void* d_ws, size_t ws_size,
                              hipStream_t stream) {
    const float* query  = (const float*)d_in[0];
    const float* refp   = (const float*)d_in[1];
    const float* inflat = (const float*)d_in[2];
    // d_in[3] = input_spatial_shapes (static, unused)
    const float* We  = (const float*)d_in[4];
    const float* SW  = (const float*)d_in[5];
    const float* SB  = (const float*)d_in[6];
    const float* AWw = (const float*)d_in[7];
    const float* ABb = (const float*)d_in[8];
    const float* VW  = (const float*)d_in[9];
    const float* Vb  = (const float*)d_in[10];
    const float* OW  = (const float*)d_in[11];
    const float* Ob  = (const float*)d_in[12];
    float* out = (float*)d_out;

    float* ws = (float*)d_ws;
    unsigned short* Vtb  = (unsigned short*)ws;                    // 5,570,560 shorts
    float* offs          = ws + 2785280;                           // 5,570,560 f
    float* awl           = offs + 5570560;                         // 2,785,280 f
    unsigned short* Qbf  = (unsigned short*)(awl + 2785280);       // 5,570,560 shorts
    unsigned short* Webf = Qbf + 5570560;                          // 1,048,576 shorts
    unsigned short* Xbf  = Webf + 1048576;                         // 5,570,560 shorts
    unsigned short* Wvbf = Xbf + 5570560;                          // 65,536 shorts
    unsigned short* OWbf = Wvbf + 65536;                           // 65,536 shorts
    unsigned short* Rbf  = OWbf + 65536;                           // 65,536 shorts
    unsigned short* atnb = Xbf;   // alias: Xbf consumed by k_value_mfma before k_sample writes

    k_cvt<<<dim3(5440, 3), 256, 0, stream>>>(query, Qbf, inflat, Xbf,
                                             We, Webf, VW, Wvbf, OW, OWbf,
                                             SW, AWw, Rbf);

    k_value_mfma<<<dim3(2, MTOT / 128), 256, 0, stream>>>(Xbf, Wvbf, Vb, Vtb);

    k_oe_mfma<<<dim3(OEN / 128, MTOT / 128), 256, 0, stream>>>(
        Qbf, Webf, Rbf, SB, ABb, offs, awl);

    k_sample<<<dim3(2720), 256, 0, stream>>>(Vtb, refp, offs, awl, atnb);

    k_out_mfma<<<dim3(2, MTOT / 128), 256, 0, stream>>>(atnb, OWbf, Ob, out);
}